// Round 1
// 724.907 us; speedup vs baseline: 1.1070x; 1.1070x over previous
//
#include <hip/hip_runtime.h>
#include <hip/hip_bf16.h>
#include <math.h>

#define NN 10000
#define EE 320000
#define ETOT (EE + NN)
#define INC 128
#define HIDC 128
#define OUTC 64
#define NH 3
#define KCL 10
#define SLOPE 0.2f
#define NPAD 10112  // 79*128, padded row count for MFMA tiles

typedef __attribute__((ext_vector_type(8))) short bf16x8;
typedef __attribute__((ext_vector_type(4))) float f32x4;

__device__ __forceinline__ float wave_sum(float v) {
  for (int off = 32; off; off >>= 1) v += __shfl_xor(v, off, 64);
  return v;
}

// bf16 bit helpers (RNE, no-NaN inputs by construction)
__device__ __forceinline__ short f2bf(float v) {
  unsigned int u = __float_as_uint(v);
  unsigned int r = (u + 0x7fffu + ((u >> 16) & 1u)) >> 16;
  return (short)r;
}
__device__ __forceinline__ float bf2f(short s) {
  return __uint_as_float(((unsigned int)(unsigned short)s) << 16);
}

// ---------- per-head edge-attr scalar: ce[h] = sum_c We[0,h*C+c]*att_e[h,c] ----------
__global__ __launch_bounds__(64) void ce_kernel(const float* __restrict__ We1,
                                                const float* __restrict__ ae1,
                                                const float* __restrict__ We2,
                                                const float* __restrict__ ae2,
                                                float* __restrict__ ce) {
  int lane = threadIdx.x;
  for (int h = 0; h < NH; h++) {
    float p = 0.f;
    for (int c = lane; c < HIDC; c += 64) p += We1[h * HIDC + c] * ae1[h * HIDC + c];
    p = wave_sum(p);
    if (lane == 0) ce[h] = p;
    float q = 0.f;
    for (int c = lane; c < OUTC; c += 64) q += We2[h * OUTC + c] * ae2[h * OUTC + c];
    q = wave_sum(q);
    if (lane == 0) ce[NH + h] = q;
  }
}

// ---------- CSR build: one atomic per edge, rank cached in epos ----------
__global__ __launch_bounds__(256) void csr_count(const int* __restrict__ dst,
                                                 int* __restrict__ counts,
                                                 int* __restrict__ epos) {
  int e = blockIdx.x * 256 + threadIdx.x;
  if (e >= ETOT) return;
  int d = (e < EE) ? dst[e] : (e - EE);
  epos[e] = atomicAdd(&counts[d], 1);
}

// 10 elements/thread serial prefix + one 1024-wide scan (21 barriers total)
__global__ __launch_bounds__(1024) void scan_kernel(const int* __restrict__ counts,
                                                    int* __restrict__ offsets) {
  __shared__ int sums[1024];
  const int PT = 10;  // 1024*10 = 10240 >= NN
  int tid = threadIdx.x;
  int base = tid * PT;
  int loc[PT];
  int run = 0;
#pragma unroll
  for (int j = 0; j < PT; j++) {
    int i = base + j;
    int v = (i < NN) ? counts[i] : 0;
    run += v;
    loc[j] = run;  // inclusive within thread
  }
  sums[tid] = run;
  __syncthreads();
  for (int off = 1; off < 1024; off <<= 1) {
    int t = (tid >= off) ? sums[tid - off] : 0;
    __syncthreads();
    sums[tid] += t;
    __syncthreads();
  }
  int excl = sums[tid] - run;  // exclusive prefix of this thread
#pragma unroll
  for (int j = 0; j < PT; j++) {
    int i = base + j;
    if (i < NN) offsets[i + 1] = excl + loc[j];
  }
  if (tid == 0) offsets[0] = 0;
}

__global__ __launch_bounds__(256) void csr_fill(const int* __restrict__ dst,
                                                const int* __restrict__ offsets,
                                                const int* __restrict__ epos,
                                                int* __restrict__ edge_ids) {
  int e = blockIdx.x * 256 + threadIdx.x;
  if (e >= ETOT) return;
  int d = (e < EE) ? dst[e] : (e - EE);
  edge_ids[offsets[d] + epos[e]] = e;
}

// ---------- node-feature GEMM via split-bf16 MFMA ----------
// C[M,Nc] = A[M,K] @ B[K,Nc], fp32 in/out. a = ah+al, b = bh+bl (bf16 split),
// C ~= ah*bh + ah*bl + al*bh (al*bl dropped, ~2^-16 relative error).
// BM=64, BN=64, BK=32; 4 waves 2x2, each wave 32x32 (2x2 frags of 16x16x32).
template <bool NANFIX>
__global__ __launch_bounds__(256) void gemm_nn_mfma(const float* __restrict__ A,
                                                    const float* __restrict__ B,
                                                    float* __restrict__ C,
                                                    int M, int K, int Nc) {
  __shared__ short Ah[64 * 32], Al[64 * 32];
  __shared__ short Bh[64 * 32], Bl[64 * 32];  // [col][k] (B^T tile)
  int tid = threadIdx.x;
  int lane = tid & 63, wave = tid >> 6;
  int wm = (wave >> 1) * 32, wn = (wave & 1) * 32;
  int bm = blockIdx.y * 64, bn = blockIdx.x * 64;
  int fr = lane & 15, fk = (lane >> 4) * 8;
  f32x4 acc[2][2] = {};
  int ar = tid >> 2, ac = (tid & 3) * 8;  // A stage: 64 rows x 32 cols, 8 floats/thr
  int bc = tid & 63, bk0 = tid >> 6;      // B stage: 32 k x 64 cols

  for (int k0 = 0; k0 < K; k0 += 32) {
    // stage A (hi/lo split)
    float av[8];
    if (bm + ar < M) {
      const float* src = A + (size_t)(bm + ar) * K + k0 + ac;
      float4 v0 = *(const float4*)src;
      float4 v1 = *(const float4*)(src + 4);
      av[0] = v0.x; av[1] = v0.y; av[2] = v0.z; av[3] = v0.w;
      av[4] = v1.x; av[5] = v1.y; av[6] = v1.z; av[7] = v1.w;
    } else {
#pragma unroll
      for (int j = 0; j < 8; j++) av[j] = 0.f;
    }
#pragma unroll
    for (int j = 0; j < 8; j++) {
      float v = av[j];
      if (NANFIX) v = (v == v) ? v : 0.f;
      short hs = f2bf(v);
      Ah[ar * 32 + ac + j] = hs;
      Al[ar * 32 + ac + j] = f2bf(v - bf2f(hs));
    }
    // stage B transposed (hi/lo split)
#pragma unroll
    for (int it = 0; it < 8; it++) {
      int kk = bk0 + it * 4;
      float v = B[(size_t)(k0 + kk) * Nc + bn + bc];
      short hs = f2bf(v);
      Bh[bc * 32 + kk] = hs;
      Bl[bc * 32 + kk] = f2bf(v - bf2f(hs));
    }
    __syncthreads();

    bf16x8 ah[2], al2[2], bh[2], bl2[2];
#pragma unroll
    for (int t = 0; t < 2; t++) {
      ah[t]  = *(const bf16x8*)&Ah[(wm + t * 16 + fr) * 32 + fk];
      al2[t] = *(const bf16x8*)&Al[(wm + t * 16 + fr) * 32 + fk];
      bh[t]  = *(const bf16x8*)&Bh[(wn + t * 16 + fr) * 32 + fk];
      bl2[t] = *(const bf16x8*)&Bl[(wn + t * 16 + fr) * 32 + fk];
    }
#pragma unroll
    for (int i = 0; i < 2; i++)
#pragma unroll
      for (int j = 0; j < 2; j++) {
        acc[i][j] = __builtin_amdgcn_mfma_f32_16x16x32_bf16(ah[i], bh[j], acc[i][j], 0, 0, 0);
        acc[i][j] = __builtin_amdgcn_mfma_f32_16x16x32_bf16(ah[i], bl2[j], acc[i][j], 0, 0, 0);
        acc[i][j] = __builtin_amdgcn_mfma_f32_16x16x32_bf16(al2[i], bh[j], acc[i][j], 0, 0, 0);
      }
    __syncthreads();
  }

  // store: C/D layout col = lane&15, row = (lane>>4)*4 + reg (m89-verified)
  int col0 = lane & 15, rq = (lane >> 4) * 4;
#pragma unroll
  for (int i = 0; i < 2; i++)
#pragma unroll
    for (int v = 0; v < 4; v++) {
      int r = bm + wm + i * 16 + rq + v;
      if (r < M) {
#pragma unroll
        for (int j = 0; j < 2; j++)
          C[(size_t)r * Nc + bn + wn + j * 16 + col0] = acc[i][j][v];
      }
    }
}

// ---------- per-node attention logits a_s, a_d ----------
template <int C>
__global__ __launch_bounds__(64) void node_aux(const float* __restrict__ hfeat,
                                               const float* __restrict__ att_s,
                                               const float* __restrict__ att_d,
                                               float* __restrict__ a_s,
                                               float* __restrict__ a_d) {
  int n = blockIdx.x, lane = threadIdx.x;
  const float* row = hfeat + (size_t)n * NH * C;
  for (int h = 0; h < NH; h++) {
    float ps = 0.f, pd = 0.f;
    for (int c = lane; c < C; c += 64) {
      float v = row[h * C + c];
      ps += v * att_s[h * C + c];
      pd += v * att_d[h * C + c];
    }
    ps = wave_sum(ps);
    pd = wave_sum(pd);
    if (lane == 0) {
      a_s[n * NH + h] = ps;
      a_d[n * NH + h] = pd;
    }
  }
}

// ---------- fused segment-softmax + aggregation: one wave per dst node ----------
// 2 passes (no max pass — logits are bounded; softmax is shift-invariant).
template <int C, bool ELU>
__global__ __launch_bounds__(64) void gat_agg(const float* __restrict__ hfeat,
                                              const float* __restrict__ a_s,
                                              const float* __restrict__ a_d,
                                              const float* __restrict__ ce,
                                              const int* __restrict__ esrc,
                                              const float* __restrict__ ea,
                                              const int* __restrict__ offsets,
                                              const int* __restrict__ edge_ids,
                                              const float* __restrict__ bias,
                                              float* __restrict__ out) {
  const int HC = NH * C;
  int n = blockIdx.x, lane = threadIdx.x;
  int beg = offsets[n], end = offsets[n + 1];
  float adn0 = a_d[n * NH + 0], adn1 = a_d[n * NH + 1], adn2 = a_d[n * NH + 2];
  float ce0 = ce[0], ce1v = ce[1], ce2 = ce[2];

  __shared__ int sh_src[64];
  __shared__ float sh_c[64][NH];

  // pass 1: per-head sum of exp (m = 0)
  float s0 = 0.f, s1 = 0.f, s2 = 0.f;
  for (int i = beg + lane; i < end; i += 64) {
    int e = edge_ids[i];
    int s;
    float a;
    if (e < EE) { s = esrc[e]; a = ea[e]; } else { s = e - EE; a = 1.f; }
    const float* asr = a_s + NH * s;
    float t0 = asr[0] + adn0 + a * ce0; t0 = t0 > 0.f ? t0 : SLOPE * t0;
    float t1 = asr[1] + adn1 + a * ce1v; t1 = t1 > 0.f ? t1 : SLOPE * t1;
    float t2 = asr[2] + adn2 + a * ce2; t2 = t2 > 0.f ? t2 : SLOPE * t2;
    s0 += __expf(t0); s1 += __expf(t1); s2 += __expf(t2);
  }
  s0 = wave_sum(s0); s1 = wave_sum(s1); s2 = wave_sum(s2);
  float di0 = 1.f / (s0 + 1e-16f), di1 = 1.f / (s1 + 1e-16f), di2 = 1.f / (s2 + 1e-16f);

  // pass 2: weighted aggregation
  float acc[HC / 64] = {};
  for (int base = beg; base < end; base += 64) {
    int i = base + lane;
    if (i < end) {
      int e = edge_ids[i];
      int s;
      float a;
      if (e < EE) { s = esrc[e]; a = ea[e]; } else { s = e - EE; a = 1.f; }
      const float* asr = a_s + NH * s;
      float t0 = asr[0] + adn0 + a * ce0; t0 = t0 > 0.f ? t0 : SLOPE * t0;
      float t1 = asr[1] + adn1 + a * ce1v; t1 = t1 > 0.f ? t1 : SLOPE * t1;
      float t2 = asr[2] + adn2 + a * ce2; t2 = t2 > 0.f ? t2 : SLOPE * t2;
      sh_src[lane] = s;
      sh_c[lane][0] = __expf(t0) * di0;
      sh_c[lane][1] = __expf(t1) * di1;
      sh_c[lane][2] = __expf(t2) * di2;
    }
    __syncthreads();
    int cnt = min(64, end - base);
    if constexpr (C == 128) {
      // float2 gather; head index is wave-uniform (= k) per accumulator pair
      for (int t = 0; t < cnt; t++) {
        int s = sh_src[t];
        const float2* hr2 = (const float2*)(hfeat + (size_t)s * HC);
        float c0 = sh_c[t][0], c1 = sh_c[t][1], c2 = sh_c[t][2];
        float2 v0 = hr2[lane], v1 = hr2[lane + 64], v2 = hr2[lane + 128];
        acc[0] += v0.x * c0; acc[1] += v0.y * c0;
        acc[2] += v1.x * c1; acc[3] += v1.y * c1;
        acc[4] += v2.x * c2; acc[5] += v2.y * c2;
      }
    } else {
      for (int t = 0; t < cnt; t++) {
        int s = sh_src[t];
        const float* hr = hfeat + (size_t)s * HC;
        float c0 = sh_c[t][0], c1 = sh_c[t][1], c2 = sh_c[t][2];
        acc[0] += hr[lane] * c0;
        acc[1] += hr[lane + 64] * c1;
        acc[2] += hr[lane + 128] * c2;
      }
    }
    __syncthreads();
  }

  if constexpr (C == 128) {
#pragma unroll
    for (int k = 0; k < 3; k++) {
      int j2 = lane + 64 * k;
      float x0 = acc[2 * k] + bias[2 * j2];
      float x1 = acc[2 * k + 1] + bias[2 * j2 + 1];
      if (ELU) {
        x0 = x0 > 0.f ? x0 : expm1f(x0);
        x1 = x1 > 0.f ? x1 : expm1f(x1);
      }
      *(float2*)&out[(size_t)n * HC + 2 * j2] = make_float2(x0, x1);
    }
  } else {
#pragma unroll
    for (int k = 0; k < 3; k++) {
      int j = lane + 64 * k;
      float v = acc[k] + bias[j];
      if (ELU) v = v > 0.f ? v : expm1f(v);
      out[(size_t)n * HC + j] = v;
    }
  }
}

// ---------- fused: row L2 normalize (192) + bf16 copy + cluster softmax head ----------
__global__ __launch_bounds__(64) void norm_phead(const float* __restrict__ h2,
                                                 float* __restrict__ z,
                                                 __hip_bfloat16* __restrict__ zb,
                                                 const float* __restrict__ Wp,
                                                 const float* __restrict__ bp,
                                                 float* __restrict__ p) {
  int n = blockIdx.x, lane = threadIdx.x;
  const float* r = h2 + (size_t)n * 192;
  float v0 = r[lane], v1 = r[lane + 64], v2 = r[lane + 128];
  float s = wave_sum(v0 * v0 + v1 * v1 + v2 * v2);
  float inv = 1.f / fmaxf(sqrtf(s), 1e-12f);
  v0 *= inv; v1 *= inv; v2 *= inv;
  float* zr = z + (size_t)n * 192;
  zr[lane] = v0;
  zr[lane + 64] = v1;
  zr[lane + 128] = v2;
  __hip_bfloat16* zbr = zb + (size_t)n * 192;
  zbr[lane] = __float2bfloat16(v0);
  zbr[lane + 64] = __float2bfloat16(v1);
  zbr[lane + 128] = __float2bfloat16(v2);

  __shared__ float logits[KCL];
  for (int j = 0; j < KCL; j++) {
    float t = v0 * Wp[lane * KCL + j] + v1 * Wp[(lane + 64) * KCL + j] +
              v2 * Wp[(lane + 128) * KCL + j];
    t = wave_sum(t);
    if (lane == 0) logits[j] = t + bp[j];
  }
  __syncthreads();
  if (lane == 0) {
    float m = -1e30f;
    for (int j = 0; j < KCL; j++) m = fmaxf(m, logits[j]);
    float ex[KCL];
    float sum = 0.f;
    for (int j = 0; j < KCL; j++) { ex[j] = expf(logits[j] - m); sum += ex[j]; }
    float invs = 1.f / sum;
    for (int j = 0; j < KCL; j++) p[(size_t)n * KCL + j] = ex[j] * invs;
  }
}

// ---------- A_hat = Zb @ Zb^T via bf16 MFMA ----------
__global__ __launch_bounds__(256) void gemm_zzT_mfma(const short* __restrict__ Zb,
                                                     float* __restrict__ C, int N) {
  __shared__ short As[128 * 32];
  __shared__ short Bs[128 * 32];
  int tid = threadIdx.x;
  int lane = tid & 63;
  int wave = tid >> 6;
  int wm = (wave >> 1) * 64, wn = (wave & 1) * 64;
  int bm = blockIdx.y * 128, bn = blockIdx.x * 128;

  f32x4 acc[4][4] = {};

  int lrow = tid >> 2;
  int lcol = (tid & 3) * 8;

  int fr = lane & 15;
  int fk = (lane >> 4) * 8;

  for (int kt = 0; kt < 6; kt++) {
    int k0 = kt * 32;
    const short* ga0 = Zb + (size_t)(bm + lrow) * 192 + k0 + lcol;
    const short* ga1 = Zb + (size_t)(bm + 64 + lrow) * 192 + k0 + lcol;
    const short* gb0 = Zb + (size_t)(bn + lrow) * 192 + k0 + lcol;
    const short* gb1 = Zb + (size_t)(bn + 64 + lrow) * 192 + k0 + lcol;
    __builtin_amdgcn_global_load_lds(
        (const __attribute__((address_space(1))) unsigned int*)ga0,
        (__attribute__((address_space(3))) unsigned int*)&As[lrow * 32 + lcol], 16, 0, 0);
    __builtin_amdgcn_global_load_lds(
        (const __attribute__((address_space(1))) unsigned int*)ga1,
        (__attribute__((address_space(3))) unsigned int*)&As[(64 + lrow) * 32 + lcol], 16, 0, 0);
    __builtin_amdgcn_global_load_lds(
        (const __attribute__((address_space(1))) unsigned int*)gb0,
        (__attribute__((address_space(3))) unsigned int*)&Bs[lrow * 32 + lcol], 16, 0, 0);
    __builtin_amdgcn_global_load_lds(
        (const __attribute__((address_space(1))) unsigned int*)gb1,
        (__attribute__((address_space(3))) unsigned int*)&Bs[(64 + lrow) * 32 + lcol], 16, 0, 0);
    __syncthreads();

    bf16x8 af[4], bfr[4];
#pragma unroll
    for (int t = 0; t < 4; t++) af[t] = *(const bf16x8*)&As[(wm + t * 16 + fr) * 32 + fk];
#pragma unroll
    for (int t = 0; t < 4; t++) bfr[t] = *(const bf16x8*)&Bs[(wn + t * 16 + fr) * 32 + fk];
#pragma unroll
    for (int i = 0; i < 4; i++)
#pragma unroll
      for (int j = 0; j < 4; j++)
        acc[i][j] = __builtin_amdgcn_mfma_f32_16x16x32_bf16(af[i], bfr[j], acc[i][j], 0, 0, 0);
    __syncthreads();
  }

  int col0 = lane & 15;
  int rquad = (lane >> 4) * 4;
#pragma unroll
  for (int i = 0; i < 4; i++) {
#pragma unroll
    for (int v = 0; v < 4; v++) {
      int r = bm + wm + i * 16 + rquad + v;
      if (r >= N) continue;
      size_t ro = (size_t)r * N;
#pragma unroll
      for (int j = 0; j < 4; j++) {
        int c = bn + wn + j * 16 + col0;
        if (c < N) C[ro + c] = acc[i][j][v];
      }
    }
  }
}

extern "C" void kernel_launch(void* const* d_in, const int* in_sizes, int n_in,
                              void* d_out, int out_size, void* d_ws, size_t ws_size,
                              hipStream_t stream) {
  const float* x = (const float*)d_in[0];
  const int* edge_index = (const int*)d_in[1];
  const float* edge_attr = (const float*)d_in[2];
  const float* W1 = (const float*)d_in[3];
  const float* att_s1 = (const float*)d_in[4];
  const float* att_d1 = (const float*)d_in[5];
  const float* We1 = (const float*)d_in[6];
  const float* att_e1 = (const float*)d_in[7];
  const float* b1 = (const float*)d_in[8];
  const float* W2 = (const float*)d_in[9];
  const float* att_s2 = (const float*)d_in[10];
  const float* att_d2 = (const float*)d_in[11];
  const float* We2 = (const float*)d_in[12];
  const float* att_e2 = (const float*)d_in[13];
  const float* b2 = (const float*)d_in[14];
  const float* Wp = (const float*)d_in[15];
  const float* bp = (const float*)d_in[16];

  const int* esrc = edge_index;        // row 0
  const int* edst = edge_index + EE;   // row 1

  float* A_hat = (float*)d_out;
  float* p_out = A_hat + (size_t)NN * NN;
  float* z_out = p_out + (size_t)NN * KCL;

  // workspace carve
  char* ws = (char*)d_ws;
  float* h1 = (float*)ws;            ws += sizeof(float) * (size_t)NN * 384;
  float* h1act = (float*)ws;         ws += sizeof(float) * (size_t)NN * 384;
  float* as1 = (float*)ws;           ws += sizeof(float) * NN * NH;
  float* ad1 = (float*)ws;           ws += sizeof(float) * NN * NH;
  float* as2 = (float*)ws;           ws += sizeof(float) * NN * NH;
  float* ad2 = (float*)ws;           ws += sizeof(float) * NN * NH;
  float* ce = (float*)ws;            ws += sizeof(float) * 8;
  int* counts = (int*)ws;            ws += sizeof(int) * NN;
  int* offsets = (int*)ws;           ws += sizeof(int) * (NN + 1);
  int* epos = (int*)ws;              ws += sizeof(int) * ETOT;
  int* edge_ids = (int*)ws;          ws += sizeof(int) * ETOT;
  __hip_bfloat16* zb = (__hip_bfloat16*)ws; ws += sizeof(__hip_bfloat16) * (size_t)NPAD * 192;

  // layer-2 feature buffers alias h1 (h1 dead after layer-1 aggregation)
  float* h2 = h1;                        // [NN,192]
  float* h2out = h1 + (size_t)NN * 192;  // [NN,192]

  hipMemsetAsync(counts, 0, sizeof(int) * NN, stream);

  ce_kernel<<<1, 64, 0, stream>>>(We1, att_e1, We2, att_e2, ce);

  int egrid = (ETOT + 255) / 256;
  csr_count<<<egrid, 256, 0, stream>>>(edst, counts, epos);
  scan_kernel<<<1, 1024, 0, stream>>>(counts, offsets);
  csr_fill<<<egrid, 256, 0, stream>>>(edst, offsets, epos, edge_ids);

  // layer 1: h1 = nan_to_num(x) @ W1   [10000,128]@[128,384]  (split-bf16 MFMA)
  gemm_nn_mfma<true><<<dim3(384 / 64, (NN + 63) / 64), 256, 0, stream>>>(x, W1, h1, NN, INC, 384);
  node_aux<HIDC><<<NN, 64, 0, stream>>>(h1, att_s1, att_d1, as1, ad1);
  gat_agg<HIDC, true><<<NN, 64, 0, stream>>>(h1, as1, ad1, ce, esrc, edge_attr,
                                             offsets, edge_ids, b1, h1act);

  // layer 2: h2 = h1act @ W2   [10000,384]@[384,192]  (split-bf16 MFMA)
  gemm_nn_mfma<false><<<dim3(192 / 64, (NN + 63) / 64), 256, 0, stream>>>(h1act, W2, h2, NN, 384, 192);
  node_aux<OUTC><<<NN, 64, 0, stream>>>(h2, att_s2, att_d2, as2, ad2);
  gat_agg<OUTC, false><<<NN, 64, 0, stream>>>(h2, as2, ad2, ce + NH, esrc, edge_attr,
                                              offsets, edge_ids, b2, h2out);

  // z = row-normalize(h2out) -> out (fp32) + zb (bf16) ; p = softmax(z @ Wp + bp)
  norm_phead<<<NN, 64, 0, stream>>>(h2out, z_out, zb, Wp, bp, p_out);

  // A_hat = zb @ zb^T -> out (bf16 MFMA, fp32 accumulate)
  gemm_zzT_mfma<<<dim3((NN + 127) / 128, (NN + 127) / 128), 256, 0, stream>>>(
      (const short*)zb, A_hat, NN);
}

// Round 2
// 686.537 us; speedup vs baseline: 1.1689x; 1.0559x over previous
//
#include <hip/hip_runtime.h>
#include <hip/hip_bf16.h>
#include <math.h>

#define NN 10000
#define EE 320000
#define ETOT (EE + NN)
#define INC 128
#define HIDC 128
#define OUTC 64
#define NH 3
#define KCL 10
#define SLOPE 0.2f
#define NPAD 10112  // 79*128, padded row count for MFMA tiles

typedef __attribute__((ext_vector_type(8))) short bf16x8;
typedef __attribute__((ext_vector_type(4))) float f32x4;

__device__ __forceinline__ float wave_sum(float v) {
  for (int off = 32; off; off >>= 1) v += __shfl_xor(v, off, 64);
  return v;
}

// bf16 bit helpers (RNE, no-NaN inputs by construction)
__device__ __forceinline__ short f2bf(float v) {
  unsigned int u = __float_as_uint(v);
  unsigned int r = (u + 0x7fffu + ((u >> 16) & 1u)) >> 16;
  return (short)r;
}
__device__ __forceinline__ float bf2f(short s) {
  return __uint_as_float(((unsigned int)(unsigned short)s) << 16);
}

// ---------- CSR count (one atomic per edge, rank cached) + fused ce ----------
// ce[h] = sum_c We[0,h*C+c]*att_e[h,c]; done by the extra last block.
__global__ __launch_bounds__(256) void csr_count(const int* __restrict__ dst,
                                                 int* __restrict__ counts,
                                                 int* __restrict__ epos,
                                                 const float* __restrict__ We1,
                                                 const float* __restrict__ ae1,
                                                 const float* __restrict__ We2,
                                                 const float* __restrict__ ae2,
                                                 float* __restrict__ ce) {
  if (blockIdx.x == gridDim.x - 1) {
    int lane = threadIdx.x;
    if (lane < 64) {
      for (int h = 0; h < NH; h++) {
        float p = 0.f;
        for (int c = lane; c < HIDC; c += 64) p += We1[h * HIDC + c] * ae1[h * HIDC + c];
        p = wave_sum(p);
        if (lane == 0) ce[h] = p;
        float q = 0.f;
        for (int c = lane; c < OUTC; c += 64) q += We2[h * OUTC + c] * ae2[h * OUTC + c];
        q = wave_sum(q);
        if (lane == 0) ce[NH + h] = q;
      }
    }
    return;
  }
  int e = blockIdx.x * 256 + threadIdx.x;
  if (e >= ETOT) return;
  int d = (e < EE) ? dst[e] : (e - EE);
  epos[e] = atomicAdd(&counts[d], 1);
}

// 10 elements/thread serial prefix + one 1024-wide scan
__global__ __launch_bounds__(1024) void scan_kernel(const int* __restrict__ counts,
                                                    int* __restrict__ offsets) {
  __shared__ int sums[1024];
  const int PT = 10;  // 1024*10 = 10240 >= NN
  int tid = threadIdx.x;
  int base = tid * PT;
  int loc[PT];
  int run = 0;
#pragma unroll
  for (int j = 0; j < PT; j++) {
    int i = base + j;
    int v = (i < NN) ? counts[i] : 0;
    run += v;
    loc[j] = run;  // inclusive within thread
  }
  sums[tid] = run;
  __syncthreads();
  for (int off = 1; off < 1024; off <<= 1) {
    int t = (tid >= off) ? sums[tid - off] : 0;
    __syncthreads();
    sums[tid] += t;
    __syncthreads();
  }
  int excl = sums[tid] - run;
#pragma unroll
  for (int j = 0; j < PT; j++) {
    int i = base + j;
    if (i < NN) offsets[i + 1] = excl + loc[j];
  }
  if (tid == 0) offsets[0] = 0;
}

__global__ __launch_bounds__(256) void csr_fill(const int* __restrict__ dst,
                                                const int* __restrict__ offsets,
                                                const int* __restrict__ epos,
                                                int* __restrict__ edge_ids) {
  int e = blockIdx.x * 256 + threadIdx.x;
  if (e >= ETOT) return;
  int d = (e < EE) ? dst[e] : (e - EE);
  edge_ids[offsets[d] + epos[e]] = e;
}

// ---------- node-feature GEMM via split-bf16 MFMA, fused att-dot epilogue ----------
// C[M,Nc] = A[M,K] @ B[K,Nc]; additionally as[r,head] += sum_cols C*att_s,
// ad[r,head] += sum_cols C*att_d (head uniform per block since 64-col tile
// lies inside one head for ch in {64,128}).
template <bool NANFIX>
__global__ __launch_bounds__(256) void gemm_nn_mfma(const float* __restrict__ A,
                                                    const float* __restrict__ B,
                                                    float* __restrict__ C,
                                                    const float* __restrict__ att_s,
                                                    const float* __restrict__ att_d,
                                                    float* __restrict__ as_out,
                                                    float* __restrict__ ad_out,
                                                    int M, int K, int Nc, int ch) {
  __shared__ short Ah[64 * 32], Al[64 * 32];
  __shared__ short Bh[64 * 32], Bl[64 * 32];  // [col][k] (B^T tile)
  int tid = threadIdx.x;
  int lane = tid & 63, wave = tid >> 6;
  int wm = (wave >> 1) * 32, wn = (wave & 1) * 32;
  int bm = blockIdx.y * 64, bn = blockIdx.x * 64;
  int fr = lane & 15, fk = (lane >> 4) * 8;
  f32x4 acc[2][2] = {};
  int ar = tid >> 2, ac = (tid & 3) * 8;  // A stage: 64 rows x 32 cols, 8 floats/thr
  int bc = tid & 63, bk0 = tid >> 6;      // B stage: 32 k x 64 cols

  for (int k0 = 0; k0 < K; k0 += 32) {
    float av[8];
    if (bm + ar < M) {
      const float* src = A + (size_t)(bm + ar) * K + k0 + ac;
      float4 v0 = *(const float4*)src;
      float4 v1 = *(const float4*)(src + 4);
      av[0] = v0.x; av[1] = v0.y; av[2] = v0.z; av[3] = v0.w;
      av[4] = v1.x; av[5] = v1.y; av[6] = v1.z; av[7] = v1.w;
    } else {
#pragma unroll
      for (int j = 0; j < 8; j++) av[j] = 0.f;
    }
#pragma unroll
    for (int j = 0; j < 8; j++) {
      float v = av[j];
      if (NANFIX) v = (v == v) ? v : 0.f;
      short hs = f2bf(v);
      Ah[ar * 32 + ac + j] = hs;
      Al[ar * 32 + ac + j] = f2bf(v - bf2f(hs));
    }
#pragma unroll
    for (int it = 0; it < 8; it++) {
      int kk = bk0 + it * 4;
      float v = B[(size_t)(k0 + kk) * Nc + bn + bc];
      short hs = f2bf(v);
      Bh[bc * 32 + kk] = hs;
      Bl[bc * 32 + kk] = f2bf(v - bf2f(hs));
    }
    __syncthreads();

    bf16x8 ah[2], al2[2], bh[2], bl2[2];
#pragma unroll
    for (int t = 0; t < 2; t++) {
      ah[t]  = *(const bf16x8*)&Ah[(wm + t * 16 + fr) * 32 + fk];
      al2[t] = *(const bf16x8*)&Al[(wm + t * 16 + fr) * 32 + fk];
      bh[t]  = *(const bf16x8*)&Bh[(wn + t * 16 + fr) * 32 + fk];
      bl2[t] = *(const bf16x8*)&Bl[(wn + t * 16 + fr) * 32 + fk];
    }
#pragma unroll
    for (int i = 0; i < 2; i++)
#pragma unroll
      for (int j = 0; j < 2; j++) {
        acc[i][j] = __builtin_amdgcn_mfma_f32_16x16x32_bf16(ah[i], bh[j], acc[i][j], 0, 0, 0);
        acc[i][j] = __builtin_amdgcn_mfma_f32_16x16x32_bf16(ah[i], bl2[j], acc[i][j], 0, 0, 0);
        acc[i][j] = __builtin_amdgcn_mfma_f32_16x16x32_bf16(al2[i], bh[j], acc[i][j], 0, 0, 0);
      }
    __syncthreads();
  }

  // store: C/D layout col = lane&15, row = (lane>>4)*4 + reg (m89-verified)
  int col0 = lane & 15, rq = (lane >> 4) * 4;
#pragma unroll
  for (int i = 0; i < 2; i++)
#pragma unroll
    for (int v = 0; v < 4; v++) {
      int r = bm + wm + i * 16 + rq + v;
      if (r < M) {
#pragma unroll
        for (int j = 0; j < 2; j++)
          C[(size_t)r * Nc + bn + wn + j * 16 + col0] = acc[i][j][v];
      }
    }

  // fused att-dot partials: reduce across the 16-lane group sharing a row
  int head = bn / ch;
  float sax[4], sdx[4];
#pragma unroll
  for (int j = 0; j < 4; j++) {
    int cidx = bn + wn + j * 16 + col0;
    sax[j] = att_s[cidx];
    sdx[j] = att_d[cidx];
  }
#pragma unroll
  for (int i = 0; i < 2; i++)
#pragma unroll
    for (int v = 0; v < 4; v++) {
      float ps = 0.f, pd = 0.f;
#pragma unroll
      for (int j = 0; j < 2; j++) {
        ps += acc[i][j][v] * sax[j];
        pd += acc[i][j][v] * sdx[j];
      }
#pragma unroll
      for (int j = 2; j < 4; j++) {
        ps += acc[i][j & 1][v] * 0.f;  // keep shape; real terms below
      }
      // full 4-term dot (j over the wave's 2 col-frags only: wave covers 32 cols
      // = 2 frags; sax[2..3] unused)
      (void)pd;
      ps = acc[i][0][v] * sax[0] + acc[i][1][v] * sax[1];
      pd = acc[i][0][v] * sdx[0] + acc[i][1][v] * sdx[1];
#pragma unroll
      for (int m = 1; m < 16; m <<= 1) {
        ps += __shfl_xor(ps, m, 64);
        pd += __shfl_xor(pd, m, 64);
      }
      int r = bm + wm + i * 16 + rq + v;
      if ((lane & 15) == 0 && r < M) {
        atomicAdd(&as_out[r * NH + head], ps);
        atomicAdd(&ad_out[r * NH + head], pd);
      }
    }
}

// ---------- fused single-pass segment-softmax + aggregation ----------
// coef = exp(t)/denom with per-(node,head) scalar denom -> accumulate
// unnormalized sum and scale at epilogue. 4 nodes per 256-thread block,
// one wave per node, shfl-broadcast (no LDS, no barriers).
template <int C, bool ELU>
__global__ __launch_bounds__(256) void gat_agg(const float* __restrict__ hfeat,
                                               const float* __restrict__ a_s,
                                               const float* __restrict__ a_d,
                                               const float* __restrict__ ce,
                                               const int* __restrict__ esrc,
                                               const float* __restrict__ ea,
                                               const int* __restrict__ offsets,
                                               const int* __restrict__ edge_ids,
                                               const float* __restrict__ bias,
                                               float* __restrict__ out) {
  const int HC = NH * C;
  int wave = threadIdx.x >> 6, lane = threadIdx.x & 63;
  int n = blockIdx.x * 4 + wave;  // NN = 2500*4 exactly
  int beg = offsets[n], end = offsets[n + 1];
  float adn0 = a_d[n * NH + 0], adn1 = a_d[n * NH + 1], adn2 = a_d[n * NH + 2];
  float ce0 = ce[0], ce1v = ce[1], ce2 = ce[2];

  float s0 = 0.f, s1 = 0.f, s2 = 0.f;
  float4 a0 = {0.f, 0.f, 0.f, 0.f}, a1 = {0.f, 0.f, 0.f, 0.f};

  for (int base = beg; base < end; base += 64) {
    int i = base + lane;
    int se = 0;
    float e0 = 0.f, e1 = 0.f, e2 = 0.f;
    if (i < end) {
      int e = edge_ids[i];
      float a;
      if (e < EE) { se = esrc[e]; a = ea[e]; } else { se = e - EE; a = 1.f; }
      const float* asr = a_s + NH * se;
      float t0 = asr[0] + adn0 + a * ce0; t0 = t0 > 0.f ? t0 : SLOPE * t0;
      float t1 = asr[1] + adn1 + a * ce1v; t1 = t1 > 0.f ? t1 : SLOPE * t1;
      float t2 = asr[2] + adn2 + a * ce2; t2 = t2 > 0.f ? t2 : SLOPE * t2;
      e0 = __expf(t0); e1 = __expf(t1); e2 = __expf(t2);
      s0 += e0; s1 += e1; s2 += e2;
    }
    int cnt = min(64, end - base);
    for (int t = 0; t < cnt; t++) {
      int s = __shfl(se, t, 64);
      float cc0 = __shfl(e0, t, 64);
      float cc1 = __shfl(e1, t, 64);
      float cc2 = __shfl(e2, t, 64);
      const float4* hr4 = (const float4*)(hfeat + (size_t)s * HC);
      if constexpr (C == 128) {
        float4 v0 = hr4[lane];  // channels 4*lane..+3, head = lane>>5
        float cA = (lane < 32) ? cc0 : cc1;
        a0.x += v0.x * cA; a0.y += v0.y * cA; a0.z += v0.z * cA; a0.w += v0.w * cA;
        if (lane < 32) {
          float4 v1 = hr4[64 + lane];  // channels 256+4*lane, head 2
          a1.x += v1.x * cc2; a1.y += v1.y * cc2; a1.z += v1.z * cc2; a1.w += v1.w * cc2;
        }
      } else {
        if (lane < 48) {
          float4 v0 = hr4[lane];  // channels 4*lane..+3, head = lane>>4
          int hd = lane >> 4;
          float cA = (hd == 0) ? cc0 : (hd == 1 ? cc1 : cc2);
          a0.x += v0.x * cA; a0.y += v0.y * cA; a0.z += v0.z * cA; a0.w += v0.w * cA;
        }
      }
    }
  }

  s0 = wave_sum(s0); s1 = wave_sum(s1); s2 = wave_sum(s2);
  float di0 = 1.f / (s0 + 1e-16f), di1 = 1.f / (s1 + 1e-16f), di2 = 1.f / (s2 + 1e-16f);

  if constexpr (C == 128) {
    float dA = (lane < 32) ? di0 : di1;
    float4 b0 = *(const float4*)&bias[4 * lane];
    float x0 = a0.x * dA + b0.x, x1 = a0.y * dA + b0.y;
    float x2 = a0.z * dA + b0.z, x3 = a0.w * dA + b0.w;
    if (ELU) {
      x0 = x0 > 0.f ? x0 : expm1f(x0);
      x1 = x1 > 0.f ? x1 : expm1f(x1);
      x2 = x2 > 0.f ? x2 : expm1f(x2);
      x3 = x3 > 0.f ? x3 : expm1f(x3);
    }
    *(float4*)&out[(size_t)n * HC + 4 * lane] = make_float4(x0, x1, x2, x3);
    if (lane < 32) {
      float4 b1 = *(const float4*)&bias[256 + 4 * lane];
      float y0 = a1.x * di2 + b1.x, y1 = a1.y * di2 + b1.y;
      float y2 = a1.z * di2 + b1.z, y3 = a1.w * di2 + b1.w;
      if (ELU) {
        y0 = y0 > 0.f ? y0 : expm1f(y0);
        y1 = y1 > 0.f ? y1 : expm1f(y1);
        y2 = y2 > 0.f ? y2 : expm1f(y2);
        y3 = y3 > 0.f ? y3 : expm1f(y3);
      }
      *(float4*)&out[(size_t)n * HC + 256 + 4 * lane] = make_float4(y0, y1, y2, y3);
    }
  } else {
    if (lane < 48) {
      int hd = lane >> 4;
      float dA = (hd == 0) ? di0 : (hd == 1 ? di1 : di2);
      float4 b0 = *(const float4*)&bias[4 * lane];
      float x0 = a0.x * dA + b0.x, x1 = a0.y * dA + b0.y;
      float x2 = a0.z * dA + b0.z, x3 = a0.w * dA + b0.w;
      if (ELU) {
        x0 = x0 > 0.f ? x0 : expm1f(x0);
        x1 = x1 > 0.f ? x1 : expm1f(x1);
        x2 = x2 > 0.f ? x2 : expm1f(x2);
        x3 = x3 > 0.f ? x3 : expm1f(x3);
      }
      *(float4*)&out[(size_t)n * HC + 4 * lane] = make_float4(x0, x1, x2, x3);
    }
  }
}

// ---------- fused: row L2 normalize (192) + bf16 copy + cluster softmax head ----------
// 4 nodes per 256-thread block; logits stay in registers (wave_sum -> all lanes).
__global__ __launch_bounds__(256) void norm_phead(const float* __restrict__ h2,
                                                  float* __restrict__ z,
                                                  __hip_bfloat16* __restrict__ zb,
                                                  const float* __restrict__ Wp,
                                                  const float* __restrict__ bp,
                                                  float* __restrict__ p) {
  int wave = threadIdx.x >> 6, lane = threadIdx.x & 63;
  int n = blockIdx.x * 4 + wave;
  const float* r = h2 + (size_t)n * 192;
  float v0 = r[lane], v1 = r[lane + 64], v2 = r[lane + 128];
  float s = wave_sum(v0 * v0 + v1 * v1 + v2 * v2);
  float inv = 1.f / fmaxf(sqrtf(s), 1e-12f);
  v0 *= inv; v1 *= inv; v2 *= inv;
  float* zr = z + (size_t)n * 192;
  zr[lane] = v0;
  zr[lane + 64] = v1;
  zr[lane + 128] = v2;
  __hip_bfloat16* zbr = zb + (size_t)n * 192;
  zbr[lane] = __float2bfloat16(v0);
  zbr[lane + 64] = __float2bfloat16(v1);
  zbr[lane + 128] = __float2bfloat16(v2);

  float lg[KCL];
#pragma unroll
  for (int j = 0; j < KCL; j++) {
    float t = v0 * Wp[lane * KCL + j] + v1 * Wp[(lane + 64) * KCL + j] +
              v2 * Wp[(lane + 128) * KCL + j];
    lg[j] = wave_sum(t) + bp[j];
  }
  if (lane == 0) {
    float m = -1e30f;
#pragma unroll
    for (int j = 0; j < KCL; j++) m = fmaxf(m, lg[j]);
    float ex[KCL];
    float sum = 0.f;
#pragma unroll
    for (int j = 0; j < KCL; j++) { ex[j] = expf(lg[j] - m); sum += ex[j]; }
    float invs = 1.f / sum;
#pragma unroll
    for (int j = 0; j < KCL; j++) p[(size_t)n * KCL + j] = ex[j] * invs;
  }
}

// ---------- A_hat = Zb @ Zb^T via bf16 MFMA (nontemporal stores) ----------
__global__ __launch_bounds__(256) void gemm_zzT_mfma(const short* __restrict__ Zb,
                                                     float* __restrict__ C, int N) {
  __shared__ short As[128 * 32];
  __shared__ short Bs[128 * 32];
  int tid = threadIdx.x;
  int lane = tid & 63;
  int wave = tid >> 6;
  int wm = (wave >> 1) * 64, wn = (wave & 1) * 64;
  int bm = blockIdx.y * 128, bn = blockIdx.x * 128;

  f32x4 acc[4][4] = {};

  int lrow = tid >> 2;
  int lcol = (tid & 3) * 8;

  int fr = lane & 15;
  int fk = (lane >> 4) * 8;

  for (int kt = 0; kt < 6; kt++) {
    int k0 = kt * 32;
    const short* ga0 = Zb + (size_t)(bm + lrow) * 192 + k0 + lcol;
    const short* ga1 = Zb + (size_t)(bm + 64 + lrow) * 192 + k0 + lcol;
    const short* gb0 = Zb + (size_t)(bn + lrow) * 192 + k0 + lcol;
    const short* gb1 = Zb + (size_t)(bn + 64 + lrow) * 192 + k0 + lcol;
    __builtin_amdgcn_global_load_lds(
        (const __attribute__((address_space(1))) unsigned int*)ga0,
        (__attribute__((address_space(3))) unsigned int*)&As[lrow * 32 + lcol], 16, 0, 0);
    __builtin_amdgcn_global_load_lds(
        (const __attribute__((address_space(1))) unsigned int*)ga1,
        (__attribute__((address_space(3))) unsigned int*)&As[(64 + lrow) * 32 + lcol], 16, 0, 0);
    __builtin_amdgcn_global_load_lds(
        (const __attribute__((address_space(1))) unsigned int*)gb0,
        (__attribute__((address_space(3))) unsigned int*)&Bs[lrow * 32 + lcol], 16, 0, 0);
    __builtin_amdgcn_global_load_lds(
        (const __attribute__((address_space(1))) unsigned int*)gb1,
        (__attribute__((address_space(3))) unsigned int*)&Bs[(64 + lrow) * 32 + lcol], 16, 0, 0);
    __syncthreads();

    bf16x8 af[4], bfr[4];
#pragma unroll
    for (int t = 0; t < 4; t++) af[t] = *(const bf16x8*)&As[(wm + t * 16 + fr) * 32 + fk];
#pragma unroll
    for (int t = 0; t < 4; t++) bfr[t] = *(const bf16x8*)&Bs[(wn + t * 16 + fr) * 32 + fk];
#pragma unroll
    for (int i = 0; i < 4; i++)
#pragma unroll
      for (int j = 0; j < 4; j++)
        acc[i][j] = __builtin_amdgcn_mfma_f32_16x16x32_bf16(af[i], bfr[j], acc[i][j], 0, 0, 0);
    __syncthreads();
  }

  int col0 = lane & 15;
  int rquad = (lane >> 4) * 4;
#pragma unroll
  for (int i = 0; i < 4; i++) {
#pragma unroll
    for (int v = 0; v < 4; v++) {
      int r = bm + wm + i * 16 + rquad + v;
      if (r >= N) continue;
      size_t ro = (size_t)r * N;
#pragma unroll
      for (int j = 0; j < 4; j++) {
        int c = bn + wn + j * 16 + col0;
        if (c < N) __builtin_nontemporal_store(acc[i][j][v], &C[ro + c]);
      }
    }
  }
}

extern "C" void kernel_launch(void* const* d_in, const int* in_sizes, int n_in,
                              void* d_out, int out_size, void* d_ws, size_t ws_size,
                              hipStream_t stream) {
  const float* x = (const float*)d_in[0];
  const int* edge_index = (const int*)d_in[1];
  const float* edge_attr = (const float*)d_in[2];
  const float* W1 = (const float*)d_in[3];
  const float* att_s1 = (const float*)d_in[4];
  const float* att_d1 = (const float*)d_in[5];
  const float* We1 = (const float*)d_in[6];
  const float* att_e1 = (const float*)d_in[7];
  const float* b1 = (const float*)d_in[8];
  const float* W2 = (const float*)d_in[9];
  const float* att_s2 = (const float*)d_in[10];
  const float* att_d2 = (const float*)d_in[11];
  const float* We2 = (const float*)d_in[12];
  const float* att_e2 = (const float*)d_in[13];
  const float* b2 = (const float*)d_in[14];
  const float* Wp = (const float*)d_in[15];
  const float* bp = (const float*)d_in[16];

  const int* esrc = edge_index;        // row 0
  const int* edst = edge_index + EE;   // row 1

  float* A_hat = (float*)d_out;
  float* p_out = A_hat + (size_t)NN * NN;
  float* z_out = p_out + (size_t)NN * KCL;

  // workspace carve (counts + as/ad contiguous for a single memset)
  char* ws = (char*)d_ws;
  float* h1 = (float*)ws;            ws += sizeof(float) * (size_t)NN * 384;
  float* h1act = (float*)ws;         ws += sizeof(float) * (size_t)NN * 384;
  int* counts = (int*)ws;            ws += sizeof(int) * NN;
  float* as1 = (float*)ws;           ws += sizeof(float) * NN * NH;
  float* ad1 = (float*)ws;           ws += sizeof(float) * NN * NH;
  float* as2 = (float*)ws;           ws += sizeof(float) * NN * NH;
  float* ad2 = (float*)ws;           ws += sizeof(float) * NN * NH;
  float* ce = (float*)ws;            ws += sizeof(float) * 8;
  int* offsets = (int*)ws;           ws += sizeof(int) * (NN + 1);
  int* epos = (int*)ws;              ws += sizeof(int) * ETOT;
  int* edge_ids = (int*)ws;          ws += sizeof(int) * ETOT;
  __hip_bfloat16* zb = (__hip_bfloat16*)ws; ws += sizeof(__hip_bfloat16) * (size_t)NPAD * 192;

  // layer-2 feature buffers alias h1 (h1 dead after layer-1 aggregation)
  float* h2 = h1;                        // [NN,192]
  float* h2out = h1 + (size_t)NN * 192;  // [NN,192]

  // zero counts + as1/ad1/as2/ad2 in one shot (contiguous)
  hipMemsetAsync(counts, 0, sizeof(int) * NN + sizeof(float) * 4 * NN * NH, stream);

  int egrid = (ETOT + 255) / 256;
  csr_count<<<egrid + 1, 256, 0, stream>>>(edst, counts, epos, We1, att_e1, We2, att_e2, ce);
  scan_kernel<<<1, 1024, 0, stream>>>(counts, offsets);
  csr_fill<<<egrid, 256, 0, stream>>>(edst, offsets, epos, edge_ids);

  // layer 1: h1 = nan_to_num(x) @ W1 + fused as1/ad1 partial dots
  gemm_nn_mfma<true><<<dim3(384 / 64, (NN + 63) / 64), 256, 0, stream>>>(
      x, W1, h1, att_s1, att_d1, as1, ad1, NN, INC, 384, HIDC);
  gat_agg<HIDC, true><<<NN / 4, 256, 0, stream>>>(h1, as1, ad1, ce, esrc, edge_attr,
                                                  offsets, edge_ids, b1, h1act);

  // layer 2: h2 = h1act @ W2 + fused as2/ad2 partial dots
  gemm_nn_mfma<false><<<dim3(192 / 64, (NN + 63) / 64), 256, 0, stream>>>(
      h1act, W2, h2, att_s2, att_d2, as2, ad2, NN, 384, 192, OUTC);
  gat_agg<OUTC, false><<<NN / 4, 256, 0, stream>>>(h2, as2, ad2, ce + NH, esrc, edge_attr,
                                                   offsets, edge_ids, b2, h2out);

  // z = row-normalize(h2out) -> out (fp32) + zb (bf16) ; p = softmax(z @ Wp + bp)
  norm_phead<<<NN / 4, 256, 0, stream>>>(h2out, z_out, zb, Wp, bp, p_out);

  // A_hat = zb @ zb^T -> out (bf16 MFMA, fp32 accumulate, nontemporal stores)
  gemm_zzT_mfma<<<dim3((NN + 127) / 128, (NN + 127) / 128), 256, 0, stream>>>(
      (const short*)zb, A_hat, NN);
}

// Round 3
// 653.522 us; speedup vs baseline: 1.2280x; 1.0505x over previous
//
#include <hip/hip_runtime.h>
#include <hip/hip_bf16.h>
#include <math.h>

#define NN 10000
#define EE 320000
#define ETOT (EE + NN)
#define INC 128
#define HIDC 128
#define OUTC 64
#define NH 3
#define KCL 10
#define SLOPE 0.2f
#define NPAD 10112  // 79*128, padded row count for MFMA tiles

typedef __attribute__((ext_vector_type(8))) short bf16x8;
typedef __attribute__((ext_vector_type(4))) float f32x4;
typedef __attribute__((ext_vector_type(16))) float f32x16;

__device__ __forceinline__ float wave_sum(float v) {
  for (int off = 32; off; off >>= 1) v += __shfl_xor(v, off, 64);
  return v;
}

// bf16 bit helpers (RNE, no-NaN inputs by construction)
__device__ __forceinline__ short f2bf(float v) {
  unsigned int u = __float_as_uint(v);
  unsigned int r = (u + 0x7fffu + ((u >> 16) & 1u)) >> 16;
  return (short)r;
}
__device__ __forceinline__ float bf2f(short s) {
  return __uint_as_float(((unsigned int)(unsigned short)s) << 16);
}

// ---------- CSR count (one atomic per edge, rank cached) + fused ce ----------
__global__ __launch_bounds__(256) void csr_count(const int* __restrict__ dst,
                                                 int* __restrict__ counts,
                                                 int* __restrict__ epos,
                                                 const float* __restrict__ We1,
                                                 const float* __restrict__ ae1,
                                                 const float* __restrict__ We2,
                                                 const float* __restrict__ ae2,
                                                 float* __restrict__ ce) {
  if (blockIdx.x == gridDim.x - 1) {
    int lane = threadIdx.x;
    if (lane < 64) {
      for (int h = 0; h < NH; h++) {
        float p = 0.f;
        for (int c = lane; c < HIDC; c += 64) p += We1[h * HIDC + c] * ae1[h * HIDC + c];
        p = wave_sum(p);
        if (lane == 0) ce[h] = p;
        float q = 0.f;
        for (int c = lane; c < OUTC; c += 64) q += We2[h * OUTC + c] * ae2[h * OUTC + c];
        q = wave_sum(q);
        if (lane == 0) ce[NH + h] = q;
      }
    }
    return;
  }
  int e = blockIdx.x * 256 + threadIdx.x;
  if (e >= ETOT) return;
  int d = (e < EE) ? dst[e] : (e - EE);
  epos[e] = atomicAdd(&counts[d], 1);
}

// 10 elements/thread serial prefix + one 1024-wide scan
__global__ __launch_bounds__(1024) void scan_kernel(const int* __restrict__ counts,
                                                    int* __restrict__ offsets) {
  __shared__ int sums[1024];
  const int PT = 10;  // 1024*10 = 10240 >= NN
  int tid = threadIdx.x;
  int base = tid * PT;
  int loc[PT];
  int run = 0;
#pragma unroll
  for (int j = 0; j < PT; j++) {
    int i = base + j;
    int v = (i < NN) ? counts[i] : 0;
    run += v;
    loc[j] = run;  // inclusive within thread
  }
  sums[tid] = run;
  __syncthreads();
  for (int off = 1; off < 1024; off <<= 1) {
    int t = (tid >= off) ? sums[tid - off] : 0;
    __syncthreads();
    sums[tid] += t;
    __syncthreads();
  }
  int excl = sums[tid] - run;
#pragma unroll
  for (int j = 0; j < PT; j++) {
    int i = base + j;
    if (i < NN) offsets[i + 1] = excl + loc[j];
  }
  if (tid == 0) offsets[0] = 0;
}

// fill packed edge records: {src, float-bits(edge_attr)} per CSR slot
__global__ __launch_bounds__(256) void csr_fill(const int* __restrict__ dst,
                                                const int* __restrict__ src,
                                                const float* __restrict__ ea,
                                                const int* __restrict__ offsets,
                                                const int* __restrict__ epos,
                                                int2* __restrict__ erec) {
  int e = blockIdx.x * 256 + threadIdx.x;
  if (e >= ETOT) return;
  int d, s;
  float a;
  if (e < EE) {
    d = dst[e]; s = src[e]; a = ea[e];
  } else {
    d = e - EE; s = e - EE; a = 1.f;
  }
  erec[offsets[d] + epos[e]] = make_int2(s, __float_as_int(a));
}

// ---------- node-feature GEMM via split-bf16 MFMA, fused att-dot epilogue ----------
template <bool NANFIX>
__global__ __launch_bounds__(256) void gemm_nn_mfma(const float* __restrict__ A,
                                                    const float* __restrict__ B,
                                                    float* __restrict__ C,
                                                    const float* __restrict__ att_s,
                                                    const float* __restrict__ att_d,
                                                    float* __restrict__ as_out,
                                                    float* __restrict__ ad_out,
                                                    int M, int K, int Nc, int ch) {
  __shared__ short Ah[64 * 32], Al[64 * 32];
  __shared__ short Bh[64 * 32], Bl[64 * 32];  // [col][k] (B^T tile)
  int tid = threadIdx.x;
  int lane = tid & 63, wave = tid >> 6;
  int wm = (wave >> 1) * 32, wn = (wave & 1) * 32;
  int bm = blockIdx.y * 64, bn = blockIdx.x * 64;
  int fr = lane & 15, fk = (lane >> 4) * 8;
  f32x4 acc[2][2] = {};
  int ar = tid >> 2, ac = (tid & 3) * 8;  // A stage: 64 rows x 32 cols
  int bc = tid & 63, bk0 = tid >> 6;      // B stage: 32 k x 64 cols

  for (int k0 = 0; k0 < K; k0 += 32) {
    float av[8];
    if (bm + ar < M) {
      const float* src = A + (size_t)(bm + ar) * K + k0 + ac;
      float4 v0 = *(const float4*)src;
      float4 v1 = *(const float4*)(src + 4);
      av[0] = v0.x; av[1] = v0.y; av[2] = v0.z; av[3] = v0.w;
      av[4] = v1.x; av[5] = v1.y; av[6] = v1.z; av[7] = v1.w;
    } else {
#pragma unroll
      for (int j = 0; j < 8; j++) av[j] = 0.f;
    }
#pragma unroll
    for (int j = 0; j < 8; j++) {
      float v = av[j];
      if (NANFIX) v = (v == v) ? v : 0.f;
      short hs = f2bf(v);
      Ah[ar * 32 + ac + j] = hs;
      Al[ar * 32 + ac + j] = f2bf(v - bf2f(hs));
    }
#pragma unroll
    for (int it = 0; it < 8; it++) {
      int kk = bk0 + it * 4;
      float v = B[(size_t)(k0 + kk) * Nc + bn + bc];
      short hs = f2bf(v);
      Bh[bc * 32 + kk] = hs;
      Bl[bc * 32 + kk] = f2bf(v - bf2f(hs));
    }
    __syncthreads();

    bf16x8 ah[2], al2[2], bh[2], bl2[2];
#pragma unroll
    for (int t = 0; t < 2; t++) {
      ah[t]  = *(const bf16x8*)&Ah[(wm + t * 16 + fr) * 32 + fk];
      al2[t] = *(const bf16x8*)&Al[(wm + t * 16 + fr) * 32 + fk];
      bh[t]  = *(const bf16x8*)&Bh[(wn + t * 16 + fr) * 32 + fk];
      bl2[t] = *(const bf16x8*)&Bl[(wn + t * 16 + fr) * 32 + fk];
    }
#pragma unroll
    for (int i = 0; i < 2; i++)
#pragma unroll
      for (int j = 0; j < 2; j++) {
        acc[i][j] = __builtin_amdgcn_mfma_f32_16x16x32_bf16(ah[i], bh[j], acc[i][j], 0, 0, 0);
        acc[i][j] = __builtin_amdgcn_mfma_f32_16x16x32_bf16(ah[i], bl2[j], acc[i][j], 0, 0, 0);
        acc[i][j] = __builtin_amdgcn_mfma_f32_16x16x32_bf16(al2[i], bh[j], acc[i][j], 0, 0, 0);
      }
    __syncthreads();
  }

  // store: C/D layout col = lane&15, row = (lane>>4)*4 + reg (m89-verified)
  int col0 = lane & 15, rq = (lane >> 4) * 4;
#pragma unroll
  for (int i = 0; i < 2; i++)
#pragma unroll
    for (int v = 0; v < 4; v++) {
      int r = bm + wm + i * 16 + rq + v;
      if (r < M) {
#pragma unroll
        for (int j = 0; j < 2; j++)
          C[(size_t)r * Nc + bn + wn + j * 16 + col0] = acc[i][j][v];
      }
    }

  // fused att-dot partials: 16-lane-group reduce, atomic into as/ad
  int head = bn / ch;
  float sax0 = att_s[bn + wn + col0], sax1 = att_s[bn + wn + 16 + col0];
  float sdx0 = att_d[bn + wn + col0], sdx1 = att_d[bn + wn + 16 + col0];
#pragma unroll
  for (int i = 0; i < 2; i++)
#pragma unroll
    for (int v = 0; v < 4; v++) {
      float ps = acc[i][0][v] * sax0 + acc[i][1][v] * sax1;
      float pd = acc[i][0][v] * sdx0 + acc[i][1][v] * sdx1;
#pragma unroll
      for (int m = 1; m < 16; m <<= 1) {
        ps += __shfl_xor(ps, m, 64);
        pd += __shfl_xor(pd, m, 64);
      }
      int r = bm + wm + i * 16 + rq + v;
      if ((lane & 15) == 0 && r < M) {
        atomicAdd(&as_out[r * NH + head], ps);
        atomicAdd(&ad_out[r * NH + head], pd);
      }
    }
}

// ---------- layer-1 fused single-pass segment-softmax + aggregation (C=128) ----------
// float2-balanced: each lane owns channels {2l,2l+1}(h0), {128+2l,...}(h1), {256+2l,...}(h2).
__global__ __launch_bounds__(256) void gat_agg_l1(const float* __restrict__ hfeat,
                                                  const float* __restrict__ a_s,
                                                  const float* __restrict__ a_d,
                                                  const float* __restrict__ ce,
                                                  const int* __restrict__ offsets,
                                                  const int2* __restrict__ erec,
                                                  const float* __restrict__ bias,
                                                  float* __restrict__ out) {
  int wave = threadIdx.x >> 6, lane = threadIdx.x & 63;
  int n = blockIdx.x * 4 + wave;  // NN = 2500*4 exactly
  int beg = offsets[n], end = offsets[n + 1];
  float adn0 = a_d[n * NH + 0], adn1 = a_d[n * NH + 1], adn2 = a_d[n * NH + 2];
  float ce0 = ce[0], ce1v = ce[1], ce2 = ce[2];

  float s0 = 0.f, s1 = 0.f, s2 = 0.f;
  float a00 = 0.f, a01 = 0.f, a10 = 0.f, a11 = 0.f, a20 = 0.f, a21 = 0.f;

  for (int base = beg; base < end; base += 64) {
    int i = base + lane;
    int se = 0;
    float e0 = 0.f, e1 = 0.f, e2 = 0.f;
    if (i < end) {
      int2 rec = erec[i];
      se = rec.x;
      float a = __int_as_float(rec.y);
      const float* asr = a_s + NH * se;
      float t0 = asr[0] + adn0 + a * ce0; t0 = t0 > 0.f ? t0 : SLOPE * t0;
      float t1 = asr[1] + adn1 + a * ce1v; t1 = t1 > 0.f ? t1 : SLOPE * t1;
      float t2 = asr[2] + adn2 + a * ce2; t2 = t2 > 0.f ? t2 : SLOPE * t2;
      e0 = __expf(t0); e1 = __expf(t1); e2 = __expf(t2);
      s0 += e0; s1 += e1; s2 += e2;
    }
    int cnt = min(64, end - base);
#pragma unroll 2
    for (int t = 0; t < cnt; t++) {
      int s = __shfl(se, t, 64);
      float c0 = __shfl(e0, t, 64);
      float c1 = __shfl(e1, t, 64);
      float c2 = __shfl(e2, t, 64);
      const float2* hr2 = (const float2*)(hfeat + (size_t)s * 384);
      float2 v0 = hr2[lane], v1 = hr2[lane + 64], v2 = hr2[lane + 128];
      a00 += v0.x * c0; a01 += v0.y * c0;
      a10 += v1.x * c1; a11 += v1.y * c1;
      a20 += v2.x * c2; a21 += v2.y * c2;
    }
  }

  s0 = wave_sum(s0); s1 = wave_sum(s1); s2 = wave_sum(s2);
  float di0 = 1.f / (s0 + 1e-16f), di1 = 1.f / (s1 + 1e-16f), di2 = 1.f / (s2 + 1e-16f);

  float2 b0 = *(const float2*)&bias[2 * lane];
  float2 b1 = *(const float2*)&bias[128 + 2 * lane];
  float2 b2 = *(const float2*)&bias[256 + 2 * lane];
  float x0 = a00 * di0 + b0.x, x1 = a01 * di0 + b0.y;
  float y0 = a10 * di1 + b1.x, y1 = a11 * di1 + b1.y;
  float z0 = a20 * di2 + b2.x, z1 = a21 * di2 + b2.y;
  x0 = x0 > 0.f ? x0 : expm1f(x0); x1 = x1 > 0.f ? x1 : expm1f(x1);
  y0 = y0 > 0.f ? y0 : expm1f(y0); y1 = y1 > 0.f ? y1 : expm1f(y1);
  z0 = z0 > 0.f ? z0 : expm1f(z0); z1 = z1 > 0.f ? z1 : expm1f(z1);
  float* orow = out + (size_t)n * 384;
  *(float2*)&orow[2 * lane] = make_float2(x0, x1);
  *(float2*)&orow[128 + 2 * lane] = make_float2(y0, y1);
  *(float2*)&orow[256 + 2 * lane] = make_float2(z0, z1);
}

// ---------- layer-2 agg (C=64) fused with L2-normalize + bf16 cast + cluster head ----------
// lane owns channels {l, l+64, l+128} (heads 0,1,2 resp.)
__global__ __launch_bounds__(256) void gat_agg_l2(const float* __restrict__ hfeat,
                                                  const float* __restrict__ a_s,
                                                  const float* __restrict__ a_d,
                                                  const float* __restrict__ ce,
                                                  const int* __restrict__ offsets,
                                                  const int2* __restrict__ erec,
                                                  const float* __restrict__ bias,
                                                  float* __restrict__ z,
                                                  __hip_bfloat16* __restrict__ zb,
                                                  const float* __restrict__ Wp,
                                                  const float* __restrict__ bp,
                                                  float* __restrict__ p) {
  int wave = threadIdx.x >> 6, lane = threadIdx.x & 63;
  int n = blockIdx.x * 4 + wave;
  int beg = offsets[n], end = offsets[n + 1];
  float adn0 = a_d[n * NH + 0], adn1 = a_d[n * NH + 1], adn2 = a_d[n * NH + 2];
  float ce0 = ce[0], ce1v = ce[1], ce2 = ce[2];

  float s0 = 0.f, s1 = 0.f, s2 = 0.f;
  float a0 = 0.f, a1 = 0.f, a2 = 0.f;

  for (int base = beg; base < end; base += 64) {
    int i = base + lane;
    int se = 0;
    float e0 = 0.f, e1 = 0.f, e2 = 0.f;
    if (i < end) {
      int2 rec = erec[i];
      se = rec.x;
      float a = __int_as_float(rec.y);
      const float* asr = a_s + NH * se;
      float t0 = asr[0] + adn0 + a * ce0; t0 = t0 > 0.f ? t0 : SLOPE * t0;
      float t1 = asr[1] + adn1 + a * ce1v; t1 = t1 > 0.f ? t1 : SLOPE * t1;
      float t2 = asr[2] + adn2 + a * ce2; t2 = t2 > 0.f ? t2 : SLOPE * t2;
      e0 = __expf(t0); e1 = __expf(t1); e2 = __expf(t2);
      s0 += e0; s1 += e1; s2 += e2;
    }
    int cnt = min(64, end - base);
#pragma unroll 2
    for (int t = 0; t < cnt; t++) {
      int s = __shfl(se, t, 64);
      float c0 = __shfl(e0, t, 64);
      float c1 = __shfl(e1, t, 64);
      float c2 = __shfl(e2, t, 64);
      const float* hr = hfeat + (size_t)s * 192;
      a0 += hr[lane] * c0;
      a1 += hr[lane + 64] * c1;
      a2 += hr[lane + 128] * c2;
    }
  }

  s0 = wave_sum(s0); s1 = wave_sum(s1); s2 = wave_sum(s2);
  float x0 = a0 / (s0 + 1e-16f) + bias[lane];
  float x1 = a1 / (s1 + 1e-16f) + bias[lane + 64];
  float x2 = a2 / (s2 + 1e-16f) + bias[lane + 128];

  // L2 normalize across the 192-ch row
  float sq = wave_sum(x0 * x0 + x1 * x1 + x2 * x2);
  float inv = 1.f / fmaxf(sqrtf(sq), 1e-12f);
  x0 *= inv; x1 *= inv; x2 *= inv;

  float* zr = z + (size_t)n * 192;
  zr[lane] = x0; zr[lane + 64] = x1; zr[lane + 128] = x2;
  __hip_bfloat16* zbr = zb + (size_t)n * 192;
  zbr[lane] = __float2bfloat16(x0);
  zbr[lane + 64] = __float2bfloat16(x1);
  zbr[lane + 128] = __float2bfloat16(x2);

  // cluster head: p = softmax(z @ Wp + bp)
  float lg[KCL];
#pragma unroll
  for (int j = 0; j < KCL; j++) {
    float t = x0 * Wp[lane * KCL + j] + x1 * Wp[(lane + 64) * KCL + j] +
              x2 * Wp[(lane + 128) * KCL + j];
    lg[j] = wave_sum(t) + bp[j];
  }
  if (lane == 0) {
    float m = -1e30f;
#pragma unroll
    for (int j = 0; j < KCL; j++) m = fmaxf(m, lg[j]);
    float ex[KCL];
    float sum = 0.f;
#pragma unroll
    for (int j = 0; j < KCL; j++) { ex[j] = expf(lg[j] - m); sum += ex[j]; }
    float invs = 1.f / sum;
#pragma unroll
    for (int j = 0; j < KCL; j++) p[(size_t)n * KCL + j] = ex[j] * invs;
  }
}

// ---------- A_hat = Zb @ Zb^T via 32x32x16 bf16 MFMA (full-line coalesced stores) ----------
// 128x128 tile / block, 4 waves 2x2, each wave 64x64 = 2x2 frags of 32x32.
// C/D layout (m74/m101): col = lane&31, row = (r&3) + 8*(r>>2) + 4*(lane>>5).
__global__ __launch_bounds__(256) void gemm_zzT_mfma(const short* __restrict__ Zb,
                                                     float* __restrict__ C, int N) {
  __shared__ short As[128 * 32];
  __shared__ short Bs[128 * 32];
  int tid = threadIdx.x;
  int lane = tid & 63;
  int wave = tid >> 6;
  int wm = (wave >> 1) * 64, wn = (wave & 1) * 64;
  int bm = blockIdx.y * 128, bn = blockIdx.x * 128;

  f32x16 acc[2][2] = {};

  int lrow = tid >> 2;
  int lcol = (tid & 3) * 8;

  int fr = lane & 31;          // fragment row/col within 32
  int fk = (lane >> 5) * 8;    // fragment k offset (K=16 per mfma)

  for (int kt = 0; kt < 6; kt++) {
    int k0 = kt * 32;
    const short* ga0 = Zb + (size_t)(bm + lrow) * 192 + k0 + lcol;
    const short* ga1 = Zb + (size_t)(bm + 64 + lrow) * 192 + k0 + lcol;
    const short* gb0 = Zb + (size_t)(bn + lrow) * 192 + k0 + lcol;
    const short* gb1 = Zb + (size_t)(bn + 64 + lrow) * 192 + k0 + lcol;
    __builtin_amdgcn_global_load_lds(
        (const __attribute__((address_space(1))) unsigned int*)ga0,
        (__attribute__((address_space(3))) unsigned int*)&As[lrow * 32 + lcol], 16, 0, 0);
    __builtin_amdgcn_global_load_lds(
        (const __attribute__((address_space(1))) unsigned int*)ga1,
        (__attribute__((address_space(3))) unsigned int*)&As[(64 + lrow) * 32 + lcol], 16, 0, 0);
    __builtin_amdgcn_global_load_lds(
        (const __attribute__((address_space(1))) unsigned int*)gb0,
        (__attribute__((address_space(3))) unsigned int*)&Bs[lrow * 32 + lcol], 16, 0, 0);
    __builtin_amdgcn_global_load_lds(
        (const __attribute__((address_space(1))) unsigned int*)gb1,
        (__attribute__((address_space(3))) unsigned int*)&Bs[(64 + lrow) * 32 + lcol], 16, 0, 0);
    __syncthreads();

    bf16x8 af[2][2], bfr[2][2];  // [row/col-frag][k-slice]
#pragma unroll
    for (int t = 0; t < 2; t++)
#pragma unroll
      for (int ks = 0; ks < 2; ks++) {
        af[t][ks] = *(const bf16x8*)&As[(wm + t * 32 + fr) * 32 + ks * 16 + fk];
        bfr[t][ks] = *(const bf16x8*)&Bs[(wn + t * 32 + fr) * 32 + ks * 16 + fk];
      }
#pragma unroll
    for (int i = 0; i < 2; i++)
#pragma unroll
      for (int j = 0; j < 2; j++)
#pragma unroll
        for (int ks = 0; ks < 2; ks++)
          acc[i][j] = __builtin_amdgcn_mfma_f32_32x32x16_bf16(af[i][ks], bfr[j][ks],
                                                              acc[i][j], 0, 0, 0);
    __syncthreads();
  }

  int col0 = lane & 31;
  int rbase = 4 * (lane >> 5);
#pragma unroll
  for (int i = 0; i < 2; i++) {
#pragma unroll
    for (int j = 0; j < 2; j++) {
      int c = bn + wn + j * 32 + col0;
      if (c >= N) continue;
#pragma unroll
      for (int r = 0; r < 16; r++) {
        int row = bm + wm + i * 32 + (r & 3) + 8 * (r >> 2) + rbase;
        if (row < N) __builtin_nontemporal_store(acc[i][j][r], &C[(size_t)row * N + c]);
      }
    }
  }
}

extern "C" void kernel_launch(void* const* d_in, const int* in_sizes, int n_in,
                              void* d_out, int out_size, void* d_ws, size_t ws_size,
                              hipStream_t stream) {
  const float* x = (const float*)d_in[0];
  const int* edge_index = (const int*)d_in[1];
  const float* edge_attr = (const float*)d_in[2];
  const float* W1 = (const float*)d_in[3];
  const float* att_s1 = (const float*)d_in[4];
  const float* att_d1 = (const float*)d_in[5];
  const float* We1 = (const float*)d_in[6];
  const float* att_e1 = (const float*)d_in[7];
  const float* b1 = (const float*)d_in[8];
  const float* W2 = (const float*)d_in[9];
  const float* att_s2 = (const float*)d_in[10];
  const float* att_d2 = (const float*)d_in[11];
  const float* We2 = (const float*)d_in[12];
  const float* att_e2 = (const float*)d_in[13];
  const float* b2 = (const float*)d_in[14];
  const float* Wp = (const float*)d_in[15];
  const float* bp = (const float*)d_in[16];

  const int* esrc = edge_index;        // row 0
  const int* edst = edge_index + EE;   // row 1

  float* A_hat = (float*)d_out;
  float* p_out = A_hat + (size_t)NN * NN;
  float* z_out = p_out + (size_t)NN * KCL;

  // workspace carve (counts + as/ad contiguous for a single memset)
  char* ws = (char*)d_ws;
  float* h1 = (float*)ws;            ws += sizeof(float) * (size_t)NN * 384;
  float* h1act = (float*)ws;         ws += sizeof(float) * (size_t)NN * 384;
  int* counts = (int*)ws;            ws += sizeof(int) * NN;
  float* as1 = (float*)ws;           ws += sizeof(float) * NN * NH;
  float* ad1 = (float*)ws;           ws += sizeof(float) * NN * NH;
  float* as2 = (float*)ws;           ws += sizeof(float) * NN * NH;
  float* ad2 = (float*)ws;           ws += sizeof(float) * NN * NH;
  float* ce = (float*)ws;            ws += sizeof(float) * 8;
  int* offsets = (int*)ws;           ws += sizeof(int) * (NN + 4);
  int* epos = (int*)ws;              ws += sizeof(int) * ETOT;
  int2* erec = (int2*)ws;            ws += sizeof(int2) * ETOT;
  __hip_bfloat16* zb = (__hip_bfloat16*)ws; ws += sizeof(__hip_bfloat16) * (size_t)NPAD * 192;

  // layer-2 feature buffer aliases h1 (h1 dead after layer-1 aggregation)
  float* h2 = h1;  // [NN,192]

  // zero counts + as1/ad1/as2/ad2 in one shot (contiguous)
  hipMemsetAsync(counts, 0, sizeof(int) * NN + sizeof(float) * 4 * NN * NH, stream);

  int egrid = (ETOT + 255) / 256;
  csr_count<<<egrid + 1, 256, 0, stream>>>(edst, counts, epos, We1, att_e1, We2, att_e2, ce);
  scan_kernel<<<1, 1024, 0, stream>>>(counts, offsets);
  csr_fill<<<egrid, 256, 0, stream>>>(edst, esrc, edge_attr, offsets, epos, erec);

  // layer 1: h1 = nan_to_num(x) @ W1 + fused as1/ad1 partial dots
  gemm_nn_mfma<true><<<dim3(384 / 64, (NN + 63) / 64), 256, 0, stream>>>(
      x, W1, h1, att_s1, att_d1, as1, ad1, NN, INC, 384, HIDC);
  gat_agg_l1<<<NN / 4, 256, 0, stream>>>(h1, as1, ad1, ce, offsets, erec, b1, h1act);

  // layer 2: h2 = h1act @ W2 + fused as2/ad2 partial dots
  gemm_nn_mfma<false><<<dim3(192 / 64, (NN + 63) / 64), 256, 0, stream>>>(
      h1act, W2, h2, att_s2, att_d2, as2, ad2, NN, 384, 192, OUTC);
  // layer-2 agg fused with normalize + bf16 cast + cluster head
  gat_agg_l2<<<NN / 4, 256, 0, stream>>>(h2, as2, ad2, ce + NH, offsets, erec, b2,
                                         z_out, zb, Wp, bp, p_out);

  // A_hat = zb @ zb^T -> out (32x32 bf16 MFMA, fp32 accumulate, nt stores)
  gemm_zzT_mfma<<<dim3((NN + 127) / 128, (NN + 127) / 128), 256, 0, stream>>>(
      (const short*)zb, A_hat, NN);
}

// Round 4
// 638.846 us; speedup vs baseline: 1.2562x; 1.0230x over previous
//
#include <hip/hip_runtime.h>
#include <hip/hip_bf16.h>
#include <math.h>

#define NN 10000
#define EE 320000
#define ETOT (EE + NN)
#define INC 128
#define HIDC 128
#define OUTC 64
#define NH 3
#define KCL 10
#define SLOPE 0.2f
#define NPAD 10112  // 79*128, padded row count for MFMA tiles

typedef __attribute__((ext_vector_type(8))) short bf16x8;
typedef __attribute__((ext_vector_type(4))) float f32x4;
typedef __attribute__((ext_vector_type(16))) float f32x16;

__device__ __forceinline__ float wave_sum(float v) {
  for (int off = 32; off; off >>= 1) v += __shfl_xor(v, off, 64);
  return v;
}

// bf16 bit helpers (RNE, no-NaN inputs by construction)
__device__ __forceinline__ short f2bf(float v) {
  unsigned int u = __float_as_uint(v);
  unsigned int r = (u + 0x7fffu + ((u >> 16) & 1u)) >> 16;
  return (short)r;
}
__device__ __forceinline__ float bf2f(short s) {
  return __uint_as_float(((unsigned int)(unsigned short)s) << 16);
}

// ---------- CSR count (one atomic per edge, rank cached) + fused ce ----------
__global__ __launch_bounds__(256) void csr_count(const int* __restrict__ dst,
                                                 int* __restrict__ counts,
                                                 int* __restrict__ epos,
                                                 const float* __restrict__ We1,
                                                 const float* __restrict__ ae1,
                                                 const float* __restrict__ We2,
                                                 const float* __restrict__ ae2,
                                                 float* __restrict__ ce) {
  if (blockIdx.x == gridDim.x - 1) {
    int lane = threadIdx.x;
    if (lane < 64) {
      for (int h = 0; h < NH; h++) {
        float p = 0.f;
        for (int c = lane; c < HIDC; c += 64) p += We1[h * HIDC + c] * ae1[h * HIDC + c];
        p = wave_sum(p);
        if (lane == 0) ce[h] = p;
        float q = 0.f;
        for (int c = lane; c < OUTC; c += 64) q += We2[h * OUTC + c] * ae2[h * OUTC + c];
        q = wave_sum(q);
        if (lane == 0) ce[NH + h] = q;
      }
    }
    return;
  }
  int e = blockIdx.x * 256 + threadIdx.x;
  if (e >= ETOT) return;
  int d = (e < EE) ? dst[e] : (e - EE);
  epos[e] = atomicAdd(&counts[d], 1);
}

// 10 elements/thread serial prefix + one 1024-wide scan
__global__ __launch_bounds__(1024) void scan_kernel(const int* __restrict__ counts,
                                                    int* __restrict__ offsets) {
  __shared__ int sums[1024];
  const int PT = 10;  // 1024*10 = 10240 >= NN
  int tid = threadIdx.x;
  int base = tid * PT;
  int loc[PT];
  int run = 0;
#pragma unroll
  for (int j = 0; j < PT; j++) {
    int i = base + j;
    int v = (i < NN) ? counts[i] : 0;
    run += v;
    loc[j] = run;  // inclusive within thread
  }
  sums[tid] = run;
  __syncthreads();
  for (int off = 1; off < 1024; off <<= 1) {
    int t = (tid >= off) ? sums[tid - off] : 0;
    __syncthreads();
    sums[tid] += t;
    __syncthreads();
  }
  int excl = sums[tid] - run;
#pragma unroll
  for (int j = 0; j < PT; j++) {
    int i = base + j;
    if (i < NN) offsets[i + 1] = excl + loc[j];
  }
  if (tid == 0) offsets[0] = 0;
}

// fill packed edge records: {src, float-bits(edge_attr)} per CSR slot
__global__ __launch_bounds__(256) void csr_fill(const int* __restrict__ dst,
                                                const int* __restrict__ src,
                                                const float* __restrict__ ea,
                                                const int* __restrict__ offsets,
                                                const int* __restrict__ epos,
                                                int2* __restrict__ erec) {
  int e = blockIdx.x * 256 + threadIdx.x;
  if (e >= ETOT) return;
  int d, s;
  float a;
  if (e < EE) {
    d = dst[e]; s = src[e]; a = ea[e];
  } else {
    d = e - EE; s = e - EE; a = 1.f;
  }
  erec[offsets[d] + epos[e]] = make_int2(s, __float_as_int(a));
}

// ---------- node-feature GEMM via split-bf16 MFMA, fused att-dot epilogue ----------
// LDS rows padded 32->40 shorts (80 B, 16B-aligned): bank stride 20 -> 2-way (free).
#define LROW 40
template <bool NANFIX>
__global__ __launch_bounds__(256) void gemm_nn_mfma(const float* __restrict__ A,
                                                    const float* __restrict__ B,
                                                    float* __restrict__ C,
                                                    const float* __restrict__ att_s,
                                                    const float* __restrict__ att_d,
                                                    float* __restrict__ as_out,
                                                    float* __restrict__ ad_out,
                                                    int M, int K, int Nc, int ch) {
  __shared__ short Ah[64 * LROW], Al[64 * LROW];
  __shared__ short Bh[64 * LROW], Bl[64 * LROW];  // [col][k] (B^T tile)
  int tid = threadIdx.x;
  int lane = tid & 63, wave = tid >> 6;
  int wm = (wave >> 1) * 32, wn = (wave & 1) * 32;
  int bm = blockIdx.y * 64, bn = blockIdx.x * 64;
  int fr = lane & 15, fk = (lane >> 4) * 8;
  f32x4 acc[2][2] = {};
  int ar = tid >> 2, ac = (tid & 3) * 8;  // A stage: 64 rows x 32 cols
  int bc = tid & 63, bk0 = tid >> 6;      // B stage: 32 k x 64 cols

  for (int k0 = 0; k0 < K; k0 += 32) {
    float av[8];
    if (bm + ar < M) {
      const float* src = A + (size_t)(bm + ar) * K + k0 + ac;
      float4 v0 = *(const float4*)src;
      float4 v1 = *(const float4*)(src + 4);
      av[0] = v0.x; av[1] = v0.y; av[2] = v0.z; av[3] = v0.w;
      av[4] = v1.x; av[5] = v1.y; av[6] = v1.z; av[7] = v1.w;
    } else {
#pragma unroll
      for (int j = 0; j < 8; j++) av[j] = 0.f;
    }
#pragma unroll
    for (int j = 0; j < 8; j++) {
      float v = av[j];
      if (NANFIX) v = (v == v) ? v : 0.f;
      short hs = f2bf(v);
      Ah[ar * LROW + ac + j] = hs;
      Al[ar * LROW + ac + j] = f2bf(v - bf2f(hs));
    }
#pragma unroll
    for (int it = 0; it < 8; it++) {
      int kk = bk0 + it * 4;
      float v = B[(size_t)(k0 + kk) * Nc + bn + bc];
      short hs = f2bf(v);
      Bh[bc * LROW + kk] = hs;
      Bl[bc * LROW + kk] = f2bf(v - bf2f(hs));
    }
    __syncthreads();

    bf16x8 ah[2], al2[2], bh[2], bl2[2];
#pragma unroll
    for (int t = 0; t < 2; t++) {
      ah[t]  = *(const bf16x8*)&Ah[(wm + t * 16 + fr) * LROW + fk];
      al2[t] = *(const bf16x8*)&Al[(wm + t * 16 + fr) * LROW + fk];
      bh[t]  = *(const bf16x8*)&Bh[(wn + t * 16 + fr) * LROW + fk];
      bl2[t] = *(const bf16x8*)&Bl[(wn + t * 16 + fr) * LROW + fk];
    }
#pragma unroll
    for (int i = 0; i < 2; i++)
#pragma unroll
      for (int j = 0; j < 2; j++) {
        acc[i][j] = __builtin_amdgcn_mfma_f32_16x16x32_bf16(ah[i], bh[j], acc[i][j], 0, 0, 0);
        acc[i][j] = __builtin_amdgcn_mfma_f32_16x16x32_bf16(ah[i], bl2[j], acc[i][j], 0, 0, 0);
        acc[i][j] = __builtin_amdgcn_mfma_f32_16x16x32_bf16(al2[i], bh[j], acc[i][j], 0, 0, 0);
      }
    __syncthreads();
  }

  // store: C/D layout col = lane&15, row = (lane>>4)*4 + reg (m89-verified)
  int col0 = lane & 15, rq = (lane >> 4) * 4;
#pragma unroll
  for (int i = 0; i < 2; i++)
#pragma unroll
    for (int v = 0; v < 4; v++) {
      int r = bm + wm + i * 16 + rq + v;
      if (r < M) {
#pragma unroll
        for (int j = 0; j < 2; j++)
          C[(size_t)r * Nc + bn + wn + j * 16 + col0] = acc[i][j][v];
      }
    }

  // fused att-dot partials: 16-lane-group reduce, atomic into as/ad
  int head = bn / ch;
  float sax0 = att_s[bn + wn + col0], sax1 = att_s[bn + wn + 16 + col0];
  float sdx0 = att_d[bn + wn + col0], sdx1 = att_d[bn + wn + 16 + col0];
#pragma unroll
  for (int i = 0; i < 2; i++)
#pragma unroll
    for (int v = 0; v < 4; v++) {
      float ps = acc[i][0][v] * sax0 + acc[i][1][v] * sax1;
      float pd = acc[i][0][v] * sdx0 + acc[i][1][v] * sdx1;
#pragma unroll
      for (int m = 1; m < 16; m <<= 1) {
        ps += __shfl_xor(ps, m, 64);
        pd += __shfl_xor(pd, m, 64);
      }
      int r = bm + wm + i * 16 + rq + v;
      if ((lane & 15) == 0 && r < M) {
        atomicAdd(&as_out[r * NH + head], ps);
        atomicAdd(&ad_out[r * NH + head], pd);
      }
    }
}

// ---------- layer-1 fused single-pass segment-softmax + aggregation (C=128) ----------
__global__ __launch_bounds__(256) void gat_agg_l1(const float* __restrict__ hfeat,
                                                  const float* __restrict__ a_s,
                                                  const float* __restrict__ a_d,
                                                  const float* __restrict__ ce,
                                                  const int* __restrict__ offsets,
                                                  const int2* __restrict__ erec,
                                                  const float* __restrict__ bias,
                                                  float* __restrict__ out) {
  int wave = threadIdx.x >> 6, lane = threadIdx.x & 63;
  int n = blockIdx.x * 4 + wave;  // NN = 2500*4 exactly
  int beg = offsets[n], end = offsets[n + 1];
  float adn0 = a_d[n * NH + 0], adn1 = a_d[n * NH + 1], adn2 = a_d[n * NH + 2];
  float ce0 = ce[0], ce1v = ce[1], ce2 = ce[2];

  float s0 = 0.f, s1 = 0.f, s2 = 0.f;
  float a00 = 0.f, a01 = 0.f, a10 = 0.f, a11 = 0.f, a20 = 0.f, a21 = 0.f;

  for (int base = beg; base < end; base += 64) {
    int i = base + lane;
    int se = 0;
    float e0 = 0.f, e1 = 0.f, e2 = 0.f;
    if (i < end) {
      int2 rec = erec[i];
      se = rec.x;
      float a = __int_as_float(rec.y);
      const float* asr = a_s + NH * se;
      float t0 = asr[0] + adn0 + a * ce0; t0 = t0 > 0.f ? t0 : SLOPE * t0;
      float t1 = asr[1] + adn1 + a * ce1v; t1 = t1 > 0.f ? t1 : SLOPE * t1;
      float t2 = asr[2] + adn2 + a * ce2; t2 = t2 > 0.f ? t2 : SLOPE * t2;
      e0 = __expf(t0); e1 = __expf(t1); e2 = __expf(t2);
      s0 += e0; s1 += e1; s2 += e2;
    }
    int cnt = min(64, end - base);
#pragma unroll 4
    for (int t = 0; t < cnt; t++) {
      int s = __shfl(se, t, 64);
      float c0 = __shfl(e0, t, 64);
      float c1 = __shfl(e1, t, 64);
      float c2 = __shfl(e2, t, 64);
      const float2* hr2 = (const float2*)(hfeat + (size_t)s * 384);
      float2 v0 = hr2[lane], v1 = hr2[lane + 64], v2 = hr2[lane + 128];
      a00 += v0.x * c0; a01 += v0.y * c0;
      a10 += v1.x * c1; a11 += v1.y * c1;
      a20 += v2.x * c2; a21 += v2.y * c2;
    }
  }

  s0 = wave_sum(s0); s1 = wave_sum(s1); s2 = wave_sum(s2);
  float di0 = 1.f / (s0 + 1e-16f), di1 = 1.f / (s1 + 1e-16f), di2 = 1.f / (s2 + 1e-16f);

  float2 b0 = *(const float2*)&bias[2 * lane];
  float2 b1 = *(const float2*)&bias[128 + 2 * lane];
  float2 b2 = *(const float2*)&bias[256 + 2 * lane];
  float x0 = a00 * di0 + b0.x, x1 = a01 * di0 + b0.y;
  float y0 = a10 * di1 + b1.x, y1 = a11 * di1 + b1.y;
  float z0 = a20 * di2 + b2.x, z1 = a21 * di2 + b2.y;
  x0 = x0 > 0.f ? x0 : expm1f(x0); x1 = x1 > 0.f ? x1 : expm1f(x1);
  y0 = y0 > 0.f ? y0 : expm1f(y0); y1 = y1 > 0.f ? y1 : expm1f(y1);
  z0 = z0 > 0.f ? z0 : expm1f(z0); z1 = z1 > 0.f ? z1 : expm1f(z1);
  float* orow = out + (size_t)n * 384;
  *(float2*)&orow[2 * lane] = make_float2(x0, x1);
  *(float2*)&orow[128 + 2 * lane] = make_float2(y0, y1);
  *(float2*)&orow[256 + 2 * lane] = make_float2(z0, z1);
}

// ---------- layer-2 agg (C=64) fused with L2-normalize + bf16 cast + cluster head ----------
__global__ __launch_bounds__(256) void gat_agg_l2(const float* __restrict__ hfeat,
                                                  const float* __restrict__ a_s,
                                                  const float* __restrict__ a_d,
                                                  const float* __restrict__ ce,
                                                  const int* __restrict__ offsets,
                                                  const int2* __restrict__ erec,
                                                  const float* __restrict__ bias,
                                                  float* __restrict__ z,
                                                  __hip_bfloat16* __restrict__ zb,
                                                  const float* __restrict__ Wp,
                                                  const float* __restrict__ bp,
                                                  float* __restrict__ p) {
  int wave = threadIdx.x >> 6, lane = threadIdx.x & 63;
  int n = blockIdx.x * 4 + wave;
  int beg = offsets[n], end = offsets[n + 1];
  float adn0 = a_d[n * NH + 0], adn1 = a_d[n * NH + 1], adn2 = a_d[n * NH + 2];
  float ce0 = ce[0], ce1v = ce[1], ce2 = ce[2];

  float s0 = 0.f, s1 = 0.f, s2 = 0.f;
  float a0 = 0.f, a1 = 0.f, a2 = 0.f;

  for (int base = beg; base < end; base += 64) {
    int i = base + lane;
    int se = 0;
    float e0 = 0.f, e1 = 0.f, e2 = 0.f;
    if (i < end) {
      int2 rec = erec[i];
      se = rec.x;
      float a = __int_as_float(rec.y);
      const float* asr = a_s + NH * se;
      float t0 = asr[0] + adn0 + a * ce0; t0 = t0 > 0.f ? t0 : SLOPE * t0;
      float t1 = asr[1] + adn1 + a * ce1v; t1 = t1 > 0.f ? t1 : SLOPE * t1;
      float t2 = asr[2] + adn2 + a * ce2; t2 = t2 > 0.f ? t2 : SLOPE * t2;
      e0 = __expf(t0); e1 = __expf(t1); e2 = __expf(t2);
      s0 += e0; s1 += e1; s2 += e2;
    }
    int cnt = min(64, end - base);
#pragma unroll 4
    for (int t = 0; t < cnt; t++) {
      int s = __shfl(se, t, 64);
      float c0 = __shfl(e0, t, 64);
      float c1 = __shfl(e1, t, 64);
      float c2 = __shfl(e2, t, 64);
      const float* hr = hfeat + (size_t)s * 192;
      a0 += hr[lane] * c0;
      a1 += hr[lane + 64] * c1;
      a2 += hr[lane + 128] * c2;
    }
  }

  s0 = wave_sum(s0); s1 = wave_sum(s1); s2 = wave_sum(s2);
  float x0 = a0 / (s0 + 1e-16f) + bias[lane];
  float x1 = a1 / (s1 + 1e-16f) + bias[lane + 64];
  float x2 = a2 / (s2 + 1e-16f) + bias[lane + 128];

  // L2 normalize across the 192-ch row
  float sq = wave_sum(x0 * x0 + x1 * x1 + x2 * x2);
  float inv = 1.f / fmaxf(sqrtf(sq), 1e-12f);
  x0 *= inv; x1 *= inv; x2 *= inv;

  float* zr = z + (size_t)n * 192;
  zr[lane] = x0; zr[lane + 64] = x1; zr[lane + 128] = x2;
  __hip_bfloat16* zbr = zb + (size_t)n * 192;
  zbr[lane] = __float2bfloat16(x0);
  zbr[lane + 64] = __float2bfloat16(x1);
  zbr[lane + 128] = __float2bfloat16(x2);

  // cluster head: p = softmax(z @ Wp + bp)
  float lg[KCL];
#pragma unroll
  for (int j = 0; j < KCL; j++) {
    float t = x0 * Wp[lane * KCL + j] + x1 * Wp[(lane + 64) * KCL + j] +
              x2 * Wp[(lane + 128) * KCL + j];
    lg[j] = wave_sum(t) + bp[j];
  }
  if (lane == 0) {
    float m = -1e30f;
#pragma unroll
    for (int j = 0; j < KCL; j++) m = fmaxf(m, lg[j]);
    float ex[KCL];
    float sum = 0.f;
#pragma unroll
    for (int j = 0; j < KCL; j++) { ex[j] = expf(lg[j] - m); sum += ex[j]; }
    float invs = 1.f / sum;
#pragma unroll
    for (int j = 0; j < KCL; j++) p[(size_t)n * KCL + j] = ex[j] * invs;
  }
}

// ---------- A_hat = Zb @ Zb^T via 32x32x16 bf16 MFMA ----------
// LDS tiles stay LINEAR (global_load_lds constraint, rule #21); bank conflicts
// fixed by XOR-swizzling the 16B slot on BOTH the global source address and the
// ds_read address: slot' = slot ^ ((row>>1)&3). Spreads 32 lanes (row stride
// 64 B) over all 8 bank-quads -> 4-way instead of 16-way.
__global__ __launch_bounds__(256) void gemm_zzT_mfma(const short* __restrict__ Zb,
                                                     float* __restrict__ C, int N) {
  __shared__ short As[128 * 32];
  __shared__ short Bs[128 * 32];
  int tid = threadIdx.x;
  int lane = tid & 63;
  int wave = tid >> 6;
  int wm = (wave >> 1) * 64, wn = (wave & 1) * 64;
  int bm = blockIdx.y * 128, bn = blockIdx.x * 128;

  f32x16 acc[2][2] = {};

  int lrow = tid >> 2;                       // LDS row this lane stages (0..63)
  int sslot = (tid & 3) ^ ((lrow >> 1) & 3); // swizzled source 16B-slot
  int scol = sslot * 8;                      // source col offset (shorts)

  int fr = lane & 31;        // fragment row within 32
  int fks = lane >> 5;       // fragment k half (0/1)

  for (int kt = 0; kt < 6; kt++) {
    int k0 = kt * 32;
    const short* ga0 = Zb + (size_t)(bm + lrow) * 192 + k0 + scol;
    const short* ga1 = Zb + (size_t)(bm + 64 + lrow) * 192 + k0 + scol;
    const short* gb0 = Zb + (size_t)(bn + lrow) * 192 + k0 + scol;
    const short* gb1 = Zb + (size_t)(bn + 64 + lrow) * 192 + k0 + scol;
    // dest is linear: lane offset = tid*16 B (row lrow, slot tid&3)
    __builtin_amdgcn_global_load_lds(
        (const __attribute__((address_space(1))) unsigned int*)ga0,
        (__attribute__((address_space(3))) unsigned int*)&As[lrow * 32 + (tid & 3) * 8], 16, 0, 0);
    __builtin_amdgcn_global_load_lds(
        (const __attribute__((address_space(1))) unsigned int*)ga1,
        (__attribute__((address_space(3))) unsigned int*)&As[(64 + lrow) * 32 + (tid & 3) * 8], 16, 0, 0);
    __builtin_amdgcn_global_load_lds(
        (const __attribute__((address_space(1))) unsigned int*)gb0,
        (__attribute__((address_space(3))) unsigned int*)&Bs[lrow * 32 + (tid & 3) * 8], 16, 0, 0);
    __builtin_amdgcn_global_load_lds(
        (const __attribute__((address_space(1))) unsigned int*)gb1,
        (__attribute__((address_space(3))) unsigned int*)&Bs[(64 + lrow) * 32 + (tid & 3) * 8], 16, 0, 0);
    __syncthreads();

    bf16x8 af[2][2], bfr[2][2];  // [row/col-frag][k-slice]
#pragma unroll
    for (int t = 0; t < 2; t++)
#pragma unroll
      for (int ks = 0; ks < 2; ks++) {
        int ra = wm + t * 32 + fr;
        int rb = wn + t * 32 + fr;
        int sa = ((ks * 2 + fks) ^ ((ra >> 1) & 3)) * 8;
        int sb = ((ks * 2 + fks) ^ ((rb >> 1) & 3)) * 8;
        af[t][ks] = *(const bf16x8*)&As[ra * 32 + sa];
        bfr[t][ks] = *(const bf16x8*)&Bs[rb * 32 + sb];
      }
#pragma unroll
    for (int i = 0; i < 2; i++)
#pragma unroll
      for (int j = 0; j < 2; j++)
#pragma unroll
        for (int ks = 0; ks < 2; ks++)
          acc[i][j] = __builtin_amdgcn_mfma_f32_32x32x16_bf16(af[i][ks], bfr[j][ks],
                                                              acc[i][j], 0, 0, 0);
    __syncthreads();
  }

  // C/D layout (m74/m101): col = lane&31, row = (r&3) + 8*(r>>2) + 4*(lane>>5)
  int col0 = lane & 31;
  int rbase = 4 * (lane >> 5);
#pragma unroll
  for (int i = 0; i < 2; i++) {
#pragma unroll
    for (int j = 0; j < 2; j++) {
      int c = bn + wn + j * 32 + col0;
      if (c >= N) continue;
#pragma unroll
      for (int r = 0; r < 16; r++) {
        int row = bm + wm + i * 32 + (r & 3) + 8 * (r >> 2) + rbase;
        if (row < N) __builtin_nontemporal_store(acc[i][j][r], &C[(size_t)row * N + c]);
      }
    }
  }
}

extern "C" void kernel_launch(void* const* d_in, const int* in_sizes, int n_in,
                              void* d_out, int out_size, void* d_ws, size_t ws_size,
                              hipStream_t stream) {
  const float* x = (const float*)d_in[0];
  const int* edge_index = (const int*)d_in[1];
  const float* edge_attr = (const float*)d_in[2];
  const float* W1 = (const float*)d_in[3];
  const float* att_s1 = (const float*)d_in[4];
  const float* att_d1 = (const float*)d_in[5];
  const float* We1 = (const float*)d_in[6];
  const float* att_e1 = (const float*)d_in[7];
  const float* b1 = (const float*)d_in[8];
  const float* W2 = (const float*)d_in[9];
  const float* att_s2 = (const float*)d_in[10];
  const float* att_d2 = (const float*)d_in[11];
  const float* We2 = (const float*)d_in[12];
  const float* att_e2 = (const float*)d_in[13];
  const float* b2 = (const float*)d_in[14];
  const float* Wp = (const float*)d_in[15];
  const float* bp = (const float*)d_in[16];

  const int* esrc = edge_index;        // row 0
  const int* edst = edge_index + EE;   // row 1

  float* A_hat = (float*)d_out;
  float* p_out = A_hat + (size_t)NN * NN;
  float* z_out = p_out + (size_t)NN * KCL;

  // workspace carve (counts + as/ad contiguous for a single memset)
  char* ws = (char*)d_ws;
  float* h1 = (float*)ws;            ws += sizeof(float) * (size_t)NN * 384;
  float* h1act = (float*)ws;         ws += sizeof(float) * (size_t)NN * 384;
  int* counts = (int*)ws;            ws += sizeof(int) * NN;
  float* as1 = (float*)ws;           ws += sizeof(float) * NN * NH;
  float* ad1 = (float*)ws;           ws += sizeof(float) * NN * NH;
  float* as2 = (float*)ws;           ws += sizeof(float) * NN * NH;
  float* ad2 = (float*)ws;           ws += sizeof(float) * NN * NH;
  float* ce = (float*)ws;            ws += sizeof(float) * 8;
  int* offsets = (int*)ws;           ws += sizeof(int) * (NN + 4);
  int* epos = (int*)ws;              ws += sizeof(int) * ETOT;
  int2* erec = (int2*)ws;            ws += sizeof(int2) * ETOT;
  __hip_bfloat16* zb = (__hip_bfloat16*)ws; ws += sizeof(__hip_bfloat16) * (size_t)NPAD * 192;

  // layer-2 feature buffer aliases h1 (h1 dead after layer-1 aggregation)
  float* h2 = h1;  // [NN,192]

  // zero counts + as1/ad1/as2/ad2 in one shot (contiguous)
  hipMemsetAsync(counts, 0, sizeof(int) * NN + sizeof(float) * 4 * NN * NH, stream);

  int egrid = (ETOT + 255) / 256;
  csr_count<<<egrid + 1, 256, 0, stream>>>(edst, counts, epos, We1, att_e1, We2, att_e2, ce);
  scan_kernel<<<1, 1024, 0, stream>>>(counts, offsets);
  csr_fill<<<egrid, 256, 0, stream>>>(edst, esrc, edge_attr, offsets, epos, erec);

  // layer 1: h1 = nan_to_num(x) @ W1 + fused as1/ad1 partial dots
  gemm_nn_mfma<true><<<dim3(384 / 64, (NN + 63) / 64), 256, 0, stream>>>(
      x, W1, h1, att_s1, att_d1, as1, ad1, NN, INC, 384, HIDC);
  gat_agg_l1<<<NN / 4, 256, 0, stream>>>(h1, as1, ad1, ce, offsets, erec, b1, h1act);

  // layer 2: h2 = h1act @ W2 + fused as2/ad2 partial dots
  gemm_nn_mfma<false><<<dim3(192 / 64, (NN + 63) / 64), 256, 0, stream>>>(
      h1act, W2, h2, att_s2, att_d2, as2, ad2, NN, 384, 192, OUTC);
  // layer-2 agg fused with normalize + bf16 cast + cluster head
  gat_agg_l2<<<NN / 4, 256, 0, stream>>>(h2, as2, ad2, ce + NH, offsets, erec, b2,
                                         z_out, zb, Wp, bp, p_out);

  // A_hat = zb @ zb^T -> out (32x32 bf16 MFMA, swizzled LDS, nt stores)
  gemm_zzT_mfma<<<dim3((NN + 127) / 128, (NN + 127) / 128), 256, 0, stream>>>(
      (const short*)zb, A_hat, NN);
}

// Round 5
// 630.075 us; speedup vs baseline: 1.2737x; 1.0139x over previous
//
#include <hip/hip_runtime.h>
#include <hip/hip_bf16.h>
#include <math.h>

#define NN 10000
#define EE 320000
#define ETOT (EE + NN)
#define INC 128
#define HIDC 128
#define OUTC 64
#define NH 3
#define KCL 10
#define SLOPE 0.2f
#define NPAD 10112   // 79*128, padded row count for MFMA tiles
#define NB_CSR 1290  // ceil(ETOT/256)
#define NB_G1 942    // (384/64) * ceil(10000/64) = 6*157

typedef __attribute__((ext_vector_type(8))) short bf16x8;
typedef __attribute__((ext_vector_type(4))) float f32x4;
typedef __attribute__((ext_vector_type(16))) float f32x16;

__device__ __forceinline__ float wave_sum(float v) {
  for (int off = 32; off; off >>= 1) v += __shfl_xor(v, off, 64);
  return v;
}
__device__ __forceinline__ float rlane_f(float v, int l) {
  return __int_as_float(__builtin_amdgcn_readlane(__float_as_int(v), l));
}

// bf16 bit helpers (RNE, no-NaN inputs by construction)
__device__ __forceinline__ short f2bf(float v) {
  unsigned int u = __float_as_uint(v);
  unsigned int r = (u + 0x7fffu + ((u >> 16) & 1u)) >> 16;
  return (short)r;
}
__device__ __forceinline__ float bf2f(short s) {
  return __uint_as_float(((unsigned int)(unsigned short)s) << 16);
}

// ---------- shared GEMM body: split-bf16 MFMA + fused att-dot epilogue ----------
// LDS rows padded 32->40 shorts (80 B): bank stride 20 -> 2-way (free).
#define LROW 40
template <bool NANFIX>
__device__ __forceinline__ void gemm_body(int bx, int by,
                                          const float* __restrict__ A,
                                          const float* __restrict__ B,
                                          float* __restrict__ C,
                                          const float* __restrict__ att_s,
                                          const float* __restrict__ att_d,
                                          float* __restrict__ as_out,
                                          float* __restrict__ ad_out,
                                          int M, int K, int Nc, int ch,
                                          short* Ah, short* Al, short* Bh, short* Bl) {
  int tid = threadIdx.x;
  int lane = tid & 63, wave = tid >> 6;
  int wm = (wave >> 1) * 32, wn = (wave & 1) * 32;
  int bm = by * 64, bn = bx * 64;
  int fr = lane & 15, fk = (lane >> 4) * 8;
  f32x4 acc[2][2] = {};
  int ar = tid >> 2, ac = (tid & 3) * 8;  // A stage: 64 rows x 32 cols
  int bc = tid & 63, bk0 = tid >> 6;      // B stage: 32 k x 64 cols

  for (int k0 = 0; k0 < K; k0 += 32) {
    float av[8];
    if (bm + ar < M) {
      const float* src = A + (size_t)(bm + ar) * K + k0 + ac;
      float4 v0 = *(const float4*)src;
      float4 v1 = *(const float4*)(src + 4);
      av[0] = v0.x; av[1] = v0.y; av[2] = v0.z; av[3] = v0.w;
      av[4] = v1.x; av[5] = v1.y; av[6] = v1.z; av[7] = v1.w;
    } else {
#pragma unroll
      for (int j = 0; j < 8; j++) av[j] = 0.f;
    }
#pragma unroll
    for (int j = 0; j < 8; j++) {
      float v = av[j];
      if (NANFIX) v = (v == v) ? v : 0.f;
      short hs = f2bf(v);
      Ah[ar * LROW + ac + j] = hs;
      Al[ar * LROW + ac + j] = f2bf(v - bf2f(hs));
    }
#pragma unroll
    for (int it = 0; it < 8; it++) {
      int kk = bk0 + it * 4;
      float v = B[(size_t)(k0 + kk) * Nc + bn + bc];
      short hs = f2bf(v);
      Bh[bc * LROW + kk] = hs;
      Bl[bc * LROW + kk] = f2bf(v - bf2f(hs));
    }
    __syncthreads();

    bf16x8 ah[2], al2[2], bh[2], bl2[2];
#pragma unroll
    for (int t = 0; t < 2; t++) {
      ah[t]  = *(const bf16x8*)&Ah[(wm + t * 16 + fr) * LROW + fk];
      al2[t] = *(const bf16x8*)&Al[(wm + t * 16 + fr) * LROW + fk];
      bh[t]  = *(const bf16x8*)&Bh[(wn + t * 16 + fr) * LROW + fk];
      bl2[t] = *(const bf16x8*)&Bl[(wn + t * 16 + fr) * LROW + fk];
    }
#pragma unroll
    for (int i = 0; i < 2; i++)
#pragma unroll
      for (int j = 0; j < 2; j++) {
        acc[i][j] = __builtin_amdgcn_mfma_f32_16x16x32_bf16(ah[i], bh[j], acc[i][j], 0, 0, 0);
        acc[i][j] = __builtin_amdgcn_mfma_f32_16x16x32_bf16(ah[i], bl2[j], acc[i][j], 0, 0, 0);
        acc[i][j] = __builtin_amdgcn_mfma_f32_16x16x32_bf16(al2[i], bh[j], acc[i][j], 0, 0, 0);
      }
    __syncthreads();
  }

  // store: C/D layout col = lane&15, row = (lane>>4)*4 + reg (m89-verified)
  int col0 = lane & 15, rq = (lane >> 4) * 4;
#pragma unroll
  for (int i = 0; i < 2; i++)
#pragma unroll
    for (int v = 0; v < 4; v++) {
      int r = bm + wm + i * 16 + rq + v;
      if (r < M) {
#pragma unroll
        for (int j = 0; j < 2; j++)
          C[(size_t)r * Nc + bn + wn + j * 16 + col0] = acc[i][j][v];
      }
    }

  // fused att-dot partials: 16-lane-group reduce, atomic into as/ad
  int head = bn / ch;
  float sax0 = att_s[bn + wn + col0], sax1 = att_s[bn + wn + 16 + col0];
  float sdx0 = att_d[bn + wn + col0], sdx1 = att_d[bn + wn + 16 + col0];
#pragma unroll
  for (int i = 0; i < 2; i++)
#pragma unroll
    for (int v = 0; v < 4; v++) {
      float ps = acc[i][0][v] * sax0 + acc[i][1][v] * sax1;
      float pd = acc[i][0][v] * sdx0 + acc[i][1][v] * sdx1;
#pragma unroll
      for (int m = 1; m < 16; m <<= 1) {
        ps += __shfl_xor(ps, m, 64);
        pd += __shfl_xor(pd, m, 64);
      }
      int r = bm + wm + i * 16 + rq + v;
      if ((lane & 15) == 0 && r < M) {
        atomicAdd(&as_out[r * NH + head], ps);
        atomicAdd(&ad_out[r * NH + head], pd);
      }
    }
}

// ---------- mega launch 1: csr_count | ce | layer-1 GEMM (independent roles) ----------
__global__ __launch_bounds__(256) void mega1(const int* __restrict__ dst,
                                             int* __restrict__ counts,
                                             int* __restrict__ epos,
                                             const float* __restrict__ We1,
                                             const float* __restrict__ ae1,
                                             const float* __restrict__ We2,
                                             const float* __restrict__ ae2,
                                             float* __restrict__ ce,
                                             const float* __restrict__ A,
                                             const float* __restrict__ B,
                                             float* __restrict__ C,
                                             const float* __restrict__ att_s,
                                             const float* __restrict__ att_d,
                                             float* __restrict__ as_out,
                                             float* __restrict__ ad_out) {
  __shared__ short Ah[64 * LROW], Al[64 * LROW];
  __shared__ short Bh[64 * LROW], Bl[64 * LROW];
  int bid = blockIdx.x;
  if (bid < NB_CSR) {
    int e = bid * 256 + threadIdx.x;
    if (e < ETOT) {
      int d = (e < EE) ? dst[e] : (e - EE);
      epos[e] = atomicAdd(&counts[d], 1);
    }
    return;
  }
  if (bid == NB_CSR) {
    int lane = threadIdx.x;
    if (lane < 64) {
      for (int h = 0; h < NH; h++) {
        float p = 0.f;
        for (int c = lane; c < HIDC; c += 64) p += We1[h * HIDC + c] * ae1[h * HIDC + c];
        p = wave_sum(p);
        if (lane == 0) ce[h] = p;
        float q = 0.f;
        for (int c = lane; c < OUTC; c += 64) q += We2[h * OUTC + c] * ae2[h * OUTC + c];
        q = wave_sum(q);
        if (lane == 0) ce[NH + h] = q;
      }
    }
    return;
  }
  int g = bid - (NB_CSR + 1);
  gemm_body<true>(g % 6, g / 6, A, B, C, att_s, att_d, as_out, ad_out,
                  NN, INC, 384, HIDC, Ah, Al, Bh, Bl);
}

// ---------- layer-2 GEMM (standalone) ----------
template <bool NANFIX>
__global__ __launch_bounds__(256) void gemm_nn_mfma(const float* __restrict__ A,
                                                    const float* __restrict__ B,
                                                    float* __restrict__ C,
                                                    const float* __restrict__ att_s,
                                                    const float* __restrict__ att_d,
                                                    float* __restrict__ as_out,
                                                    float* __restrict__ ad_out,
                                                    int M, int K, int Nc, int ch) {
  __shared__ short Ah[64 * LROW], Al[64 * LROW];
  __shared__ short Bh[64 * LROW], Bl[64 * LROW];
  gemm_body<NANFIX>(blockIdx.x, blockIdx.y, A, B, C, att_s, att_d, as_out, ad_out,
                    M, K, Nc, ch, Ah, Al, Bh, Bl);
}

// ---------- scan: LDS-staged coalesced loads/stores, 10/thread serial + 1024-wide scan ----------
__global__ __launch_bounds__(1024) void scan_kernel(const int* __restrict__ counts,
                                                    int* __restrict__ offsets) {
  __shared__ int buf[10240];  // 40 KB
  __shared__ int sums[1024];
  const int PT = 10;
  int tid = threadIdx.x;
  for (int i = tid; i < 10240; i += 1024) buf[i] = (i < NN) ? counts[i] : 0;
  __syncthreads();
  int base = tid * PT;
  int run = 0;
#pragma unroll
  for (int j = 0; j < PT; j++) {
    run += buf[base + j];
    buf[base + j] = run;  // inclusive within thread
  }
  sums[tid] = run;
  __syncthreads();
  for (int off = 1; off < 1024; off <<= 1) {
    int t = (tid >= off) ? sums[tid - off] : 0;
    __syncthreads();
    sums[tid] += t;
    __syncthreads();
  }
  int excl = sums[tid] - run;
#pragma unroll
  for (int j = 0; j < PT; j++) buf[base + j] += excl;
  __syncthreads();
  for (int i = tid; i < 10240; i += 1024)
    if (i < NN) offsets[i + 1] = buf[i];
  if (tid == 0) offsets[0] = 0;
}

// fill packed edge records: {src, float-bits(edge_attr)} per CSR slot
__global__ __launch_bounds__(256) void csr_fill(const int* __restrict__ dst,
                                                const int* __restrict__ src,
                                                const float* __restrict__ ea,
                                                const int* __restrict__ offsets,
                                                const int* __restrict__ epos,
                                                int2* __restrict__ erec) {
  int e = blockIdx.x * 256 + threadIdx.x;
  if (e >= ETOT) return;
  int d, s;
  float a;
  if (e < EE) {
    d = dst[e]; s = src[e]; a = ea[e];
  } else {
    d = e - EE; s = e - EE; a = 1.f;
  }
  erec[offsets[d] + epos[e]] = make_int2(s, __float_as_int(a));
}

// ---------- layer-1 fused single-pass segment-softmax + aggregation (C=128) ----------
__global__ __launch_bounds__(256) void gat_agg_l1(const float* __restrict__ hfeat,
                                                  const float* __restrict__ a_s,
                                                  const float* __restrict__ a_d,
                                                  const float* __restrict__ ce,
                                                  const int* __restrict__ offsets,
                                                  const int2* __restrict__ erec,
                                                  const float* __restrict__ bias,
                                                  float* __restrict__ out) {
  int wave = threadIdx.x >> 6, lane = threadIdx.x & 63;
  int n = blockIdx.x * 4 + wave;  // NN = 2500*4 exactly
  int beg = offsets[n], end = offsets[n + 1];
  float adn0 = a_d[n * NH + 0], adn1 = a_d[n * NH + 1], adn2 = a_d[n * NH + 2];
  float ce0 = ce[0], ce1v = ce[1], ce2 = ce[2];

  float s0 = 0.f, s1 = 0.f, s2 = 0.f;
  float a00 = 0.f, a01 = 0.f, a10 = 0.f, a11 = 0.f, a20 = 0.f, a21 = 0.f;

  for (int base = beg; base < end; base += 64) {
    int i = base + lane;
    int se = 0;
    float e0 = 0.f, e1 = 0.f, e2 = 0.f;
    if (i < end) {
      int2 rec = erec[i];
      se = rec.x;
      float a = __int_as_float(rec.y);
      const float* asr = a_s + NH * se;
      float t0 = asr[0] + adn0 + a * ce0; t0 = t0 > 0.f ? t0 : SLOPE * t0;
      float t1 = asr[1] + adn1 + a * ce1v; t1 = t1 > 0.f ? t1 : SLOPE * t1;
      float t2 = asr[2] + adn2 + a * ce2; t2 = t2 > 0.f ? t2 : SLOPE * t2;
      e0 = __expf(t0); e1 = __expf(t1); e2 = __expf(t2);
      s0 += e0; s1 += e1; s2 += e2;
    }
    int cnt = min(64, end - base);
#pragma unroll 4
    for (int t = 0; t < cnt; t++) {
      // wave-uniform broadcast via readlane (SALU) instead of ds_bpermute
      int s = __builtin_amdgcn_readlane(se, t);
      float c0 = rlane_f(e0, t), c1 = rlane_f(e1, t), c2 = rlane_f(e2, t);
      const float2* hr2 = (const float2*)(hfeat + (size_t)s * 384);
      float2 v0 = hr2[lane], v1 = hr2[lane + 64], v2 = hr2[lane + 128];
      a00 += v0.x * c0; a01 += v0.y * c0;
      a10 += v1.x * c1; a11 += v1.y * c1;
      a20 += v2.x * c2; a21 += v2.y * c2;
    }
  }

  s0 = wave_sum(s0); s1 = wave_sum(s1); s2 = wave_sum(s2);
  float di0 = 1.f / (s0 + 1e-16f), di1 = 1.f / (s1 + 1e-16f), di2 = 1.f / (s2 + 1e-16f);

  float2 b0 = *(const float2*)&bias[2 * lane];
  float2 b1 = *(const float2*)&bias[128 + 2 * lane];
  float2 b2 = *(const float2*)&bias[256 + 2 * lane];
  float x0 = a00 * di0 + b0.x, x1 = a01 * di0 + b0.y;
  float y0 = a10 * di1 + b1.x, y1 = a11 * di1 + b1.y;
  float z0 = a20 * di2 + b2.x, z1 = a21 * di2 + b2.y;
  x0 = x0 > 0.f ? x0 : expm1f(x0); x1 = x1 > 0.f ? x1 : expm1f(x1);
  y0 = y0 > 0.f ? y0 : expm1f(y0); y1 = y1 > 0.f ? y1 : expm1f(y1);
  z0 = z0 > 0.f ? z0 : expm1f(z0); z1 = z1 > 0.f ? z1 : expm1f(z1);
  float* orow = out + (size_t)n * 384;
  *(float2*)&orow[2 * lane] = make_float2(x0, x1);
  *(float2*)&orow[128 + 2 * lane] = make_float2(y0, y1);
  *(float2*)&orow[256 + 2 * lane] = make_float2(z0, z1);
}

// ---------- layer-2 agg (C=64) fused with L2-normalize + bf16 cast + cluster head ----------
__global__ __launch_bounds__(256) void gat_agg_l2(const float* __restrict__ hfeat,
                                                  const float* __restrict__ a_s,
                                                  const float* __restrict__ a_d,
                                                  const float* __restrict__ ce,
                                                  const int* __restrict__ offsets,
                                                  const int2* __restrict__ erec,
                                                  const float* __restrict__ bias,
                                                  float* __restrict__ z,
                                                  __hip_bfloat16* __restrict__ zb,
                                                  const float* __restrict__ Wp,
                                                  const float* __restrict__ bp,
                                                  float* __restrict__ p) {
  int wave = threadIdx.x >> 6, lane = threadIdx.x & 63;
  int n = blockIdx.x * 4 + wave;
  int beg = offsets[n], end = offsets[n + 1];
  float adn0 = a_d[n * NH + 0], adn1 = a_d[n * NH + 1], adn2 = a_d[n * NH + 2];
  float ce0 = ce[0], ce1v = ce[1], ce2 = ce[2];

  float s0 = 0.f, s1 = 0.f, s2 = 0.f;
  float a0 = 0.f, a1 = 0.f, a2 = 0.f;

  for (int base = beg; base < end; base += 64) {
    int i = base + lane;
    int se = 0;
    float e0 = 0.f, e1 = 0.f, e2 = 0.f;
    if (i < end) {
      int2 rec = erec[i];
      se = rec.x;
      float a = __int_as_float(rec.y);
      const float* asr = a_s + NH * se;
      float t0 = asr[0] + adn0 + a * ce0; t0 = t0 > 0.f ? t0 : SLOPE * t0;
      float t1 = asr[1] + adn1 + a * ce1v; t1 = t1 > 0.f ? t1 : SLOPE * t1;
      float t2 = asr[2] + adn2 + a * ce2; t2 = t2 > 0.f ? t2 : SLOPE * t2;
      e0 = __expf(t0); e1 = __expf(t1); e2 = __expf(t2);
      s0 += e0; s1 += e1; s2 += e2;
    }
    int cnt = min(64, end - base);
#pragma unroll 4
    for (int t = 0; t < cnt; t++) {
      int s = __builtin_amdgcn_readlane(se, t);
      float c0 = rlane_f(e0, t), c1 = rlane_f(e1, t), c2 = rlane_f(e2, t);
      const float* hr = hfeat + (size_t)s * 192;
      a0 += hr[lane] * c0;
      a1 += hr[lane + 64] * c1;
      a2 += hr[lane + 128] * c2;
    }
  }

  s0 = wave_sum(s0); s1 = wave_sum(s1); s2 = wave_sum(s2);
  float x0 = a0 / (s0 + 1e-16f) + bias[lane];
  float x1 = a1 / (s1 + 1e-16f) + bias[lane + 64];
  float x2 = a2 / (s2 + 1e-16f) + bias[lane + 128];

  // L2 normalize across the 192-ch row
  float sq = wave_sum(x0 * x0 + x1 * x1 + x2 * x2);
  float inv = 1.f / fmaxf(sqrtf(sq), 1e-12f);
  x0 *= inv; x1 *= inv; x2 *= inv;

  float* zr = z + (size_t)n * 192;
  zr[lane] = x0; zr[lane + 64] = x1; zr[lane + 128] = x2;
  __hip_bfloat16* zbr = zb + (size_t)n * 192;
  zbr[lane] = __float2bfloat16(x0);
  zbr[lane + 64] = __float2bfloat16(x1);
  zbr[lane + 128] = __float2bfloat16(x2);

  // cluster head: p = softmax(z @ Wp + bp)
  float lg[KCL];
#pragma unroll
  for (int j = 0; j < KCL; j++) {
    float t = x0 * Wp[lane * KCL + j] + x1 * Wp[(lane + 64) * KCL + j] +
              x2 * Wp[(lane + 128) * KCL + j];
    lg[j] = wave_sum(t) + bp[j];
  }
  if (lane == 0) {
    float m = -1e30f;
#pragma unroll
    for (int j = 0; j < KCL; j++) m = fmaxf(m, lg[j]);
    float ex[KCL];
    float sum = 0.f;
#pragma unroll
    for (int j = 0; j < KCL; j++) { ex[j] = expf(lg[j] - m); sum += ex[j]; }
    float invs = 1.f / sum;
#pragma unroll
    for (int j = 0; j < KCL; j++) p[(size_t)n * KCL + j] = ex[j] * invs;
  }
}

// ---------- A_hat = Zb @ Zb^T via 32x32x16 bf16 MFMA ----------
// Linear LDS dest (global_load_lds, rule #21); 16B-slot XOR swizzle applied to
// BOTH global source and ds_read: slot' = slot ^ ((row>>1)&3) -> 4-way max.
__global__ __launch_bounds__(256) void gemm_zzT_mfma(const short* __restrict__ Zb,
                                                     float* __restrict__ C, int N) {
  __shared__ short As[128 * 32];
  __shared__ short Bs[128 * 32];
  int tid = threadIdx.x;
  int lane = tid & 63;
  int wave = tid >> 6;
  int wm = (wave >> 1) * 64, wn = (wave & 1) * 64;
  int bm = blockIdx.y * 128, bn = blockIdx.x * 128;

  f32x16 acc[2][2] = {};

  int lrow = tid >> 2;                       // LDS row this lane stages (0..63)
  int sslot = (tid & 3) ^ ((lrow >> 1) & 3); // swizzled source 16B-slot
  int scol = sslot * 8;

  int fr = lane & 31;        // fragment row within 32
  int fks = lane >> 5;       // fragment k half (0/1)

  for (int kt = 0; kt < 6; kt++) {
    int k0 = kt * 32;
    const short* ga0 = Zb + (size_t)(bm + lrow) * 192 + k0 + scol;
    const short* ga1 = Zb + (size_t)(bm + 64 + lrow) * 192 + k0 + scol;
    const short* gb0 = Zb + (size_t)(bn + lrow) * 192 + k0 + scol;
    const short* gb1 = Zb + (size_t)(bn + 64 + lrow) * 192 + k0 + scol;
    __builtin_amdgcn_global_load_lds(
        (const __attribute__((address_space(1))) unsigned int*)ga0,
        (__attribute__((address_space(3))) unsigned int*)&As[lrow * 32 + (tid & 3) * 8], 16, 0, 0);
    __builtin_amdgcn_global_load_lds(
        (const __attribute__((address_space(1))) unsigned int*)ga1,
        (__attribute__((address_space(3))) unsigned int*)&As[(64 + lrow) * 32 + (tid & 3) * 8], 16, 0, 0);
    __builtin_amdgcn_global_load_lds(
        (const __attribute__((address_space(1))) unsigned int*)gb0,
        (__attribute__((address_space(3))) unsigned int*)&Bs[lrow * 32 + (tid & 3) * 8], 16, 0, 0);
    __builtin_amdgcn_global_load_lds(
        (const __attribute__((address_space(1))) unsigned int*)gb1,
        (__attribute__((address_space(3))) unsigned int*)&Bs[(64 + lrow) * 32 + (tid & 3) * 8], 16, 0, 0);
    __syncthreads();

    bf16x8 af[2][2], bfr[2][2];
#pragma unroll
    for (int t = 0; t < 2; t++)
#pragma unroll
      for (int ks = 0; ks < 2; ks++) {
        int ra = wm + t * 32 + fr;
        int rb = wn + t * 32 + fr;
        int sa = ((ks * 2 + fks) ^ ((ra >> 1) & 3)) * 8;
        int sb = ((ks * 2 + fks) ^ ((rb >> 1) & 3)) * 8;
        af[t][ks] = *(const bf16x8*)&As[ra * 32 + sa];
        bfr[t][ks] = *(const bf16x8*)&Bs[rb * 32 + sb];
      }
#pragma unroll
    for (int i = 0; i < 2; i++)
#pragma unroll
      for (int j = 0; j < 2; j++)
#pragma unroll
        for (int ks = 0; ks < 2; ks++)
          acc[i][j] = __builtin_amdgcn_mfma_f32_32x32x16_bf16(af[i][ks], bfr[j][ks],
                                                              acc[i][j], 0, 0, 0);
    __syncthreads();
  }

  // C/D layout (m74/m101): col = lane&31, row = (r&3) + 8*(r>>2) + 4*(lane>>5)
  int col0 = lane & 31;
  int rbase = 4 * (lane >> 5);
#pragma unroll
  for (int i = 0; i < 2; i++) {
#pragma unroll
    for (int j = 0; j < 2; j++) {
      int c = bn + wn + j * 32 + col0;
      if (c >= N) continue;
#pragma unroll
      for (int r = 0; r < 16; r++) {
        int row = bm + wm + i * 32 + (r & 3) + 8 * (r >> 2) + rbase;
        if (row < N) __builtin_nontemporal_store(acc[i][j][r], &C[(size_t)row * N + c]);
      }
    }
  }
}

extern "C" void kernel_launch(void* const* d_in, const int* in_sizes, int n_in,
                              void* d_out, int out_size, void* d_ws, size_t ws_size,
                              hipStream_t stream) {
  const float* x = (const float*)d_in[0];
  const int* edge_index = (const int*)d_in[1];
  const float* edge_attr = (const float*)d_in[2];
  const float* W1 = (const float*)d_in[3];
  const float* att_s1 = (const float*)d_in[4];
  const float* att_d1 = (const float*)d_in[5];
  const float* We1 = (const float*)d_in[6];
  const float* att_e1 = (const float*)d_in[7];
  const float* b1 = (const float*)d_in[8];
  const float* W2 = (const float*)d_in[9];
  const float* att_s2 = (const float*)d_in[10];
  const float* att_d2 = (const float*)d_in[11];
  const float* We2 = (const float*)d_in[12];
  const float* att_e2 = (const float*)d_in[13];
  const float* b2 = (const float*)d_in[14];
  const float* Wp = (const float*)d_in[15];
  const float* bp = (const float*)d_in[16];

  const int* esrc = edge_index;        // row 0
  const int* edst = edge_index + EE;   // row 1

  float* A_hat = (float*)d_out;
  float* p_out = A_hat + (size_t)NN * NN;
  float* z_out = p_out + (size_t)NN * KCL;

  // workspace carve (counts + as/ad contiguous for a single memset)
  char* ws = (char*)d_ws;
  float* h1 = (float*)ws;            ws += sizeof(float) * (size_t)NN * 384;
  float* h1act = (float*)ws;         ws += sizeof(float) * (size_t)NN * 384;
  int* counts = (int*)ws;            ws += sizeof(int) * NN;
  float* as1 = (float*)ws;           ws += sizeof(float) * NN * NH;
  float* ad1 = (float*)ws;           ws += sizeof(float) * NN * NH;
  float* as2 = (float*)ws;           ws += sizeof(float) * NN * NH;
  float* ad2 = (float*)ws;           ws += sizeof(float) * NN * NH;
  float* ce = (float*)ws;            ws += sizeof(float) * 8;
  int* offsets = (int*)ws;           ws += sizeof(int) * (NN + 4);
  int* epos = (int*)ws;              ws += sizeof(int) * ETOT;
  int2* erec = (int2*)ws;            ws += sizeof(int2) * ETOT;
  __hip_bfloat16* zb = (__hip_bfloat16*)ws; ws += sizeof(__hip_bfloat16) * (size_t)NPAD * 192;

  // layer-2 feature buffer aliases h1 (h1 dead after layer-1 aggregation)
  float* h2 = h1;  // [NN,192]

  // zero counts + as1/ad1/as2/ad2 in one shot (contiguous)
  hipMemsetAsync(counts, 0, sizeof(int) * NN + sizeof(float) * 4 * NN * NH, stream);

  // mega1: csr_count | ce | layer-1 GEMM — all independent, one launch
  mega1<<<NB_CSR + 1 + NB_G1, 256, 0, stream>>>(edst, counts, epos,
                                                We1, att_e1, We2, att_e2, ce,
                                                x, W1, h1, att_s1, att_d1, as1, ad1);
  scan_kernel<<<1, 1024, 0, stream>>>(counts, offsets);
  csr_fill<<<NB_CSR, 256, 0, stream>>>(edst, esrc, edge_attr, offsets, epos, erec);

  gat_agg_l1<<<NN / 4, 256, 0, stream>>>(h1, as1, ad1, ce, offsets, erec, b1, h1act);

  // layer 2: h2 = h1act @ W2 + fused as2/ad2 partial dots
  gemm_nn_mfma<false><<<dim3(192 / 64, (NN + 63) / 64), 256, 0, stream>>>(
      h1act, W2, h2, att_s2, att_d2, as2, ad2, NN, 384, 192, OUTC);
  // layer-2 agg fused with normalize + bf16 cast + cluster head
  gat_agg_l2<<<NN / 4, 256, 0, stream>>>(h2, as2, ad2, ce + NH, offsets, erec, b2,
                                         z_out, zb, Wp, bp, p_out);

  // A_hat = zb @ zb^T -> out (32x32 bf16 MFMA, swizzled LDS, nt stores)
  gemm_zzT_mfma<<<dim3((NN + 127) / 128, (NN + 127) / 128), 256, 0, stream>>>(
      (const short*)zb, A_hat, NN);
}